// Round 4
// baseline (496.210 us; speedup 1.0000x reference)
//
#include <hip/hip_runtime.h>
#include <math.h>

#define EMBED 768
#define FFN_D 3072
#define TSEQ 4096
#define NHEAD 12
#define DHEAD 64
#define CQKV 2304   // 3*EMBED
#define NSPLIT 4

typedef _Float16 f16;
typedef __attribute__((ext_vector_type(4))) _Float16 f16x4;
typedef __attribute__((ext_vector_type(8))) _Float16 f16x8;
typedef __attribute__((ext_vector_type(4))) float f32x4;

// async global->LDS, 16B per lane; lds base must be wave-uniform, lane i lands at base + i*16
__device__ __forceinline__ void gload16(const f16* g, f16* lds) {
    __builtin_amdgcn_global_load_lds((const __attribute__((address_space(1))) void*)g,
                                     (__attribute__((address_space(3))) void*)lds, 16, 0, 0);
}

// ---------------- transpose + fp32->fp16 convert: W[din][dout] -> WT[dout][din]
__global__ __launch_bounds__(256) void tconv_kernel(const float* __restrict__ W,
                                                    f16* __restrict__ WT,
                                                    int din, int dout) {
    __shared__ float tile[32][33];
    const int j0 = blockIdx.x * 32;   // dout
    const int i0 = blockIdx.y * 32;   // din
    const int tx = threadIdx.x & 31;
    const int ty = threadIdx.x >> 5;  // 0..7
#pragma unroll
    for (int rr = ty; rr < 32; rr += 8)
        tile[rr][tx] = W[(size_t)(i0 + rr) * dout + j0 + tx];
    __syncthreads();
#pragma unroll
    for (int rr = ty; rr < 32; rr += 8)
        WT[(size_t)(j0 + rr) * din + i0 + tx] = (f16)tile[tx][rr];
}

// ---------------- f16 transpose of the V section of qkv -> vT[h*64+d][t]
__global__ __launch_bounds__(256) void vtrans_kernel(const f16* __restrict__ qkv,
                                                     f16* __restrict__ vT) {
    __shared__ f16 tile[32][34];
    const int t0 = blockIdx.x * 32;   // seq
    const int c0 = blockIdx.y * 32;   // channel 0..767
    const int tx = threadIdx.x & 31;
    const int ty = threadIdx.x >> 5;
#pragma unroll
    for (int rr = ty; rr < 32; rr += 8)
        tile[rr][tx] = qkv[(size_t)(t0 + rr) * CQKV + 2 * EMBED + c0 + tx];
    __syncthreads();
#pragma unroll
    for (int rr = ty; rr < 32; rr += 8)
        vT[(size_t)(c0 + rr) * TSEQ + t0 + tx] = tile[tx][rr];
}

// ---------------- concat 3 bias vectors of 768 into [2304]
__global__ void concat3_kernel(const float* __restrict__ a, const float* __restrict__ b,
                               const float* __restrict__ c, float* __restrict__ o) {
    int i = blockIdx.x * 256 + threadIdx.x;
    if (i < 768) o[i] = a[i];
    else if (i < 1536) o[i] = b[i - 768];
    else if (i < 2304) o[i] = c[i - 1536];
}

// ---------------- LayerNorm row kernel (768 wide), writes f32 + f16
__global__ __launch_bounds__(256) void ln_kernel(const float* __restrict__ x,
                                                 const float* __restrict__ g,
                                                 const float* __restrict__ b,
                                                 float* __restrict__ hf,
                                                 f16* __restrict__ hh) {
    const int row = blockIdx.x;
    const float* xr = x + (size_t)row * EMBED;
    const int t = threadIdx.x;
    float v0 = xr[t], v1 = xr[t + 256], v2 = xr[t + 512];
    float s = v0 + v1 + v2;
#pragma unroll
    for (int m = 1; m < 64; m <<= 1) s += __shfl_xor(s, m);
    __shared__ float red[4], red2[4];
    const int wid = t >> 6, lane = t & 63;
    if (lane == 0) red[wid] = s;
    __syncthreads();
    float mean = (red[0] + red[1] + red[2] + red[3]) * (1.0f / 768.0f);
    float d0 = v0 - mean, d1 = v1 - mean, d2 = v2 - mean;
    float ss = d0 * d0 + d1 * d1 + d2 * d2;
#pragma unroll
    for (int m = 1; m < 64; m <<= 1) ss += __shfl_xor(ss, m);
    if (lane == 0) red2[wid] = ss;
    __syncthreads();
    float inv = rsqrtf((red2[0] + red2[1] + red2[2] + red2[3]) * (1.0f / 768.0f) + 1e-5f);
    float o0 = d0 * inv * g[t] + b[t];
    float o1 = d1 * inv * g[t + 256] + b[t + 256];
    float o2 = d2 * inv * g[t + 512] + b[t + 512];
    size_t base = (size_t)row * EMBED;
    hf[base + t] = o0; hf[base + t + 256] = o1; hf[base + t + 512] = o2;
    hh[base + t] = (f16)o0; hh[base + t + 256] = (f16)o1; hh[base + t + 512] = (f16)o2;
}

// ---------------- GEMM: C[M][N] = A[M][K] * BT[N][K]^T + bias
// global_load_lds width-16 staging (m97 recipe), unpadded [128][32] LDS
// EPI 0: out fp16    EPI 1: out fp32 = acc+bias+res    EPI 2: out fp16 = gelu(acc+bias)
template <int EPI>
__global__ __launch_bounds__(256) void gemm_kernel(const f16* __restrict__ A,
                                                   const f16* __restrict__ BT,
                                                   const float* __restrict__ bias,
                                                   const float* __restrict__ res,
                                                   float* __restrict__ outf,
                                                   f16* __restrict__ outh,
                                                   int M, int N, int K) {
    __shared__ __align__(16) f16 As[128][32];
    __shared__ __align__(16) f16 Bs[128][32];
    const int t = threadIdx.x;
    const int m0 = blockIdx.y * 128;
    const int n0 = blockIdx.x * 128;
    const int wid = t >> 6;
    const int lane = t & 63;
    const int wm = (wid >> 1) * 64;
    const int wn = (wid & 1) * 64;
    const int lr = lane & 15;
    const int lk = (lane >> 4) * 8;
    const int srow = lane >> 2;        // 0..15 within a 16-row DMA call
    const int scol = (lane & 3) * 8;   // k-offset within call

    f32x4 zero = {0.f, 0.f, 0.f, 0.f};
    f32x4 acc[4][4];
#pragma unroll
    for (int i = 0; i < 4; i++)
#pragma unroll
        for (int j = 0; j < 4; j++) acc[i][j] = zero;

    // per-wave staging rows: [wid*32, wid*32+32), two 16-row DMA calls each for A and B
    const f16* Ap = A + (size_t)(m0 + wid * 32 + srow) * K + scol;
    const f16* Bp = BT + (size_t)(n0 + wid * 32 + srow) * K + scol;

    for (int k0 = 0; k0 < K; k0 += 32) {
        __syncthreads();
        gload16(Ap + k0, &As[wid * 32][0]);
        gload16(Ap + (size_t)16 * K + k0, &As[wid * 32 + 16][0]);
        gload16(Bp + k0, &Bs[wid * 32][0]);
        gload16(Bp + (size_t)16 * K + k0, &Bs[wid * 32 + 16][0]);
        __syncthreads();
        f16x8 af[4], bf[4];
#pragma unroll
        for (int i = 0; i < 4; i++) af[i] = *(const f16x8*)&As[wm + i * 16 + lr][lk];
#pragma unroll
        for (int j = 0; j < 4; j++) bf[j] = *(const f16x8*)&Bs[wn + j * 16 + lr][lk];
#pragma unroll
        for (int i = 0; i < 4; i++)
#pragma unroll
            for (int j = 0; j < 4; j++)
                acc[i][j] = __builtin_amdgcn_mfma_f32_16x16x32_f16(af[i], bf[j], acc[i][j], 0, 0, 0);
    }

    const int q4 = (lane >> 4) * 4;
#pragma unroll
    for (int i = 0; i < 4; i++) {
        const int row = m0 + wm + i * 16 + q4;
#pragma unroll
        for (int j = 0; j < 4; j++) {
            const int col = n0 + wn + j * 16 + lr;
            const float bv = bias[col];
#pragma unroll
            for (int r = 0; r < 4; r++) {
                float v = acc[i][j][r] + bv;
                size_t idx = (size_t)(row + r) * N + col;
                if (EPI == 0) {
                    outh[idx] = (f16)v;
                } else if (EPI == 1) {
                    outf[idx] = v + res[idx];
                } else {
                    float gl = 0.5f * v * (1.0f + erff(v * 0.70710678118654752f));
                    outh[idx] = (f16)gl;
                }
            }
        }
    }
}

// ---------------- barrier-free flash attention (S^T orientation), split-K partials
// S^T = mfma(A=K, B=Q); P^T exits in B-operand layout (with k-dim permutation
// key = s*32 + quad*4 + {e | 16+e-4}, matched by the V^T A-frag loads) so PV needs
// no LDS round-trip. No __shared__, no __syncthreads anywhere.
// Opart: [NSPLIT][TSEQ][768] fp32 unnormalized O^T-written. ml: [NSPLIT][TSEQ][NHEAD]
__global__ __launch_bounds__(256) void attn_kernel(const f16* __restrict__ qkv,
                                                   const f16* __restrict__ vT,
                                                   float* __restrict__ Opart,
                                                   float2* __restrict__ ml) {
    const int h  = blockIdx.x;                    // 0..11
    const int qb = (gridDim.y - 1) - blockIdx.y;  // longest blocks dispatched first
    const int sp = blockIdx.z;
    const int q0 = qb * 128;
    const int t = threadIdx.x;
    const int wid = t >> 6;
    const int lane = t & 63;
    const int lr = lane & 15;
    const int quad = lane >> 4;

    const int nkb = 2 * qb + 2;
    const int chunk = (nkb + NSPLIT - 1) / NSPLIT;
    const int kb0 = sp * chunk;
    const int kb1 = min(nkb, kb0 + chunk);
    const int wrow0 = q0 + wid * 32;              // first q-row of this wave
    const float sc2 = 0.125f * 1.4426950408889634f;   // 1/sqrt(64) * log2(e)

    // loop-invariant Q fragments (B-operand: n = q = qt*16+lr, k = d = dh*32+quad*8+e)
    f16x8 qf[2][2];
#pragma unroll
    for (int qt = 0; qt < 2; qt++)
#pragma unroll
        for (int dh = 0; dh < 2; dh++)
            qf[qt][dh] = *(const f16x8*)(qkv + (size_t)(wrow0 + qt * 16 + lr) * CQKV
                                         + h * DHEAD + dh * 32 + quad * 8);

    float m_i[2] = {-INFINITY, -INFINITY};
    float l_i[2] = {0.f, 0.f};
    f32x4 zero = {0.f, 0.f, 0.f, 0.f};
    f32x4 o[4][2];   // O^T tiles: [dt][qt], row d = dt*16+quad*4+r, col q = qt*16+lr
#pragma unroll
    for (int dt = 0; dt < 4; dt++)
#pragma unroll
        for (int qt = 0; qt < 2; qt++) o[dt][qt] = zero;

    for (int kb = kb0; kb < kb1; ++kb) {
        const int k0 = kb * 64;
        if (k0 > wrow0 + 31) break;   // wave-uniform; k0,wrow0 mult-of-32 => active waves have k0<=wrow0

        // S^T[key][q] per wave: 64 keys x 32 q
        f32x4 s[4][2];
#pragma unroll
        for (int kt = 0; kt < 4; kt++)
#pragma unroll
            for (int qt = 0; qt < 2; qt++) s[kt][qt] = zero;
#pragma unroll
        for (int dh = 0; dh < 2; dh++) {
            f16x8 kf[4];   // A-operand: m = key = kt*16+lr, k = d = dh*32+quad*8+e
#pragma unroll
            for (int kt = 0; kt < 4; kt++)
                kf[kt] = *(const f16x8*)(qkv + (size_t)(k0 + kt * 16 + lr) * CQKV
                                         + EMBED + h * DHEAD + dh * 32 + quad * 8);
#pragma unroll
            for (int kt = 0; kt < 4; kt++)
#pragma unroll
                for (int qt = 0; qt < 2; qt++)
                    s[kt][qt] = __builtin_amdgcn_mfma_f32_16x16x32_f16(kf[kt], qf[qt][dh], s[kt][qt], 0, 0, 0);
        }

        // scale into log2 domain (+ causal mask only on boundary tiles)
        if (k0 + 63 > wrow0) {
#pragma unroll
            for (int kt = 0; kt < 4; kt++)
#pragma unroll
                for (int qt = 0; qt < 2; qt++)
#pragma unroll
                    for (int r = 0; r < 4; r++) {
                        int key = k0 + kt * 16 + quad * 4 + r;
                        int row = wrow0 + qt * 16 + lr;
                        float v = s[kt][qt][r] * sc2;
                        s[kt][qt][r] = (key > row) ? -INFINITY : v;
                    }
        } else {
#pragma unroll
            for (int kt = 0; kt < 4; kt++)
#pragma unroll
                for (int qt = 0; qt < 2; qt++)
#pragma unroll
                    for (int r = 0; r < 4; r++) s[kt][qt][r] *= sc2;
        }

        // online softmax per q-row (qt,lr): 16 in-reg values + 2 cross-quad shuffles
        float al[2];
#pragma unroll
        for (int qt = 0; qt < 2; qt++) {
            float mx = -INFINITY;
#pragma unroll
            for (int kt = 0; kt < 4; kt++)
#pragma unroll
                for (int r = 0; r < 4; r++) mx = fmaxf(mx, s[kt][qt][r]);
            mx = fmaxf(mx, __shfl_xor(mx, 16));
            mx = fmaxf(mx, __shfl_xor(mx, 32));
            float mn = fmaxf(m_i[qt], mx);
            al[qt] = exp2f(m_i[qt] - mn);   // 0 on first visit
            m_i[qt] = mn;
        }
        // P^T = 2^(s-m), packed directly into PV B-frags (k-permuted)
        float rs[2] = {0.f, 0.f};
        f16x8 pf[2][2];   // [kstep][qt]
#pragma unroll
        for (int kt = 0; kt < 4; kt++)
#pragma unroll
            for (int qt = 0; qt < 2; qt++)
#pragma unroll
                for (int r = 0; r < 4; r++) {
                    float pe = exp2f(s[kt][qt][r] - m_i[qt]);
                    rs[qt] += pe;
                    pf[kt >> 1][qt][(kt & 1) * 4 + r] = (f16)pe;
                }
#pragma unroll
        for (int qt = 0; qt < 2; qt++) {
            float v = rs[qt];
            v += __shfl_xor(v, 16);
            v += __shfl_xor(v, 32);
            l_i[qt] = l_i[qt] * al[qt] + v;
        }
        // rescale O^T, then O^T += V^T @ P^T
#pragma unroll
        for (int dt = 0; dt < 4; dt++)
#pragma unroll
            for (int qt = 0; qt < 2; qt++)
#pragma unroll
                for (int r = 0; r < 4; r++) o[dt][qt][r] *= al[qt];
#pragma unroll
        for (int s2 = 0; s2 < 2; s2++)
#pragma unroll
            for (int dt = 0; dt < 4; dt++) {
                // A-operand: m = d = dt*16+lr, k-perm: key = k0+s2*32+quad*4+{e,16+e-4}
                const f16* vr = vT + (size_t)(h * DHEAD + dt * 16 + lr) * TSEQ + k0 + s2 * 32 + quad * 4;
                f16x4 vlo = *(const f16x4*)vr;
                f16x4 vhi = *(const f16x4*)(vr + 16);
                f16x8 vf;
#pragma unroll
                for (int e = 0; e < 4; e++) { vf[e] = vlo[e]; vf[e + 4] = vhi[e]; }
#pragma unroll
                for (int qt = 0; qt < 2; qt++)
                    o[dt][qt] = __builtin_amdgcn_mfma_f32_16x16x32_f16(vf, pf[s2][qt], o[dt][qt], 0, 0, 0);
            }
    }

    // store partials: O^T tile (dt,qt) reg r = contiguous d -> 16B vector stores
#pragma unroll
    for (int dt = 0; dt < 4; dt++)
#pragma unroll
        for (int qt = 0; qt < 2; qt++) {
            int row = wrow0 + qt * 16 + lr;
            float* dst = Opart + ((size_t)sp * TSEQ + row) * EMBED + h * DHEAD + dt * 16 + quad * 4;
            *(f32x4*)dst = o[dt][qt];
        }
#pragma unroll
    for (int qt = 0; qt < 2; qt++)
        if (quad == 0) {
            int row = wrow0 + qt * 16 + lr;
            ml[((size_t)sp * TSEQ + row) * NHEAD + h] = make_float2(m_i[qt], l_i[qt]);
        }
}

// ---------------- merge split-K partials -> ctx f16
__global__ __launch_bounds__(256) void attn_merge_kernel(const float* __restrict__ Opart,
                                                         const float2* __restrict__ ml,
                                                         f16* __restrict__ ctx) {
    const int row = blockIdx.x;
    const int t = threadIdx.x;
    __shared__ float wgt[NSPLIT][NHEAD];
    if (t < NHEAD) {
        float m[NSPLIT], l[NSPLIT];
        float M = -INFINITY;
#pragma unroll
        for (int s = 0; s < NSPLIT; s++) {
            float2 v = ml[((size_t)s * TSEQ + row) * NHEAD + t];
            m[s] = v.x; l[s] = v.y;
            M = fmaxf(M, m[s]);
        }
        float L = 0.f;
        float w[NSPLIT];
#pragma unroll
        for (int s = 0; s < NSPLIT; s++) {
            w[s] = exp2f(m[s] - M);
            L += l[s] * w[s];
        }
        float rL = 1.0f / L;
#pragma unroll
        for (int s = 0; s < NSPLIT; s++) wgt[s][t] = w[s] * rL;
    }
    __syncthreads();
#pragma unroll
    for (int p = 0; p < 3; p++) {
        int c = t + p * 256;
        int h = c >> 6;
        float acc = 0.f;
#pragma unroll
        for (int s = 0; s < NSPLIT; s++)
            acc += wgt[s][h] * Opart[((size_t)s * TSEQ + row) * EMBED + c];
        ctx[(size_t)row * EMBED + c] = (f16)acc;
    }
}

extern "C" void kernel_launch(void* const* d_in, const int* in_sizes, int n_in,
                              void* d_out, int out_size, void* d_ws, size_t ws_size,
                              hipStream_t stream) {
    const float* x     = (const float*)d_in[0];
    const float* Wq    = (const float*)d_in[1];
    const float* bq    = (const float*)d_in[2];
    const float* Wk    = (const float*)d_in[3];
    const float* bk    = (const float*)d_in[4];
    const float* Wv    = (const float*)d_in[5];
    const float* bv    = (const float*)d_in[6];
    const float* Wo    = (const float*)d_in[7];
    const float* bo    = (const float*)d_in[8];
    const float* ln1_g = (const float*)d_in[9];
    const float* ln1_b = (const float*)d_in[10];
    const float* ln2_g = (const float*)d_in[11];
    const float* ln2_b = (const float*)d_in[12];
    const float* W1    = (const float*)d_in[13];
    const float* b1    = (const float*)d_in[14];
    const float* W2    = (const float*)d_in[15];
    const float* b2    = (const float*)d_in[16];

    char* p = (char*)d_ws;
    auto alloc = [&](size_t bytes) -> void* {
        void* r = (void*)p;
        p += (bytes + 255) & ~(size_t)255;
        return r;
    };
    f16*   WqkvT = (f16*)alloc((size_t)CQKV * EMBED * 2);   // [2304][768]
    f16*   WoT   = (f16*)alloc((size_t)EMBED * EMBED * 2);  // [768][768]
    f16*   W1T   = (f16*)alloc((size_t)FFN_D * EMBED * 2);  // [3072][768]
    f16*   W2T   = (f16*)alloc((size_t)EMBED * FFN_D * 2);  // [768][3072]
    float* bqkv  = (float*)alloc((size_t)CQKV * 4);
    float* hf    = (float*)alloc((size_t)TSEQ * EMBED * 4);
    f16*   hh    = (f16*)alloc((size_t)TSEQ * EMBED * 2);
    f16*   qkv   = (f16*)alloc((size_t)TSEQ * CQKV * 2);
    f16*   vT    = (f16*)alloc((size_t)EMBED * TSEQ * 2);   // [h*64+d][t]
    f16*   ctx   = (f16*)alloc((size_t)TSEQ * EMBED * 2);
    float* x2    = (float*)alloc((size_t)TSEQ * EMBED * 4);
    float* h2f   = (float*)alloc((size_t)TSEQ * EMBED * 4);
    f16*   h2h   = (f16*)alloc((size_t)TSEQ * EMBED * 2);
    f16*   m1    = (f16*)alloc((size_t)TSEQ * FFN_D * 2);

    // split-K attention partials ALIAS the post-attention buffers (x2..m1 span
    // 56.7 MB >= 50.3+1.6 MB; attention+merge complete before x2 is written)
    float*  Opart = x2;                                        // [NSPLIT][TSEQ][768] f32
    float2* mlbuf = (float2*)(x2 + (size_t)NSPLIT * TSEQ * EMBED);

    dim3 blk(256);
    tconv_kernel<<<dim3(EMBED / 32, EMBED / 32), blk, 0, stream>>>(Wq, WqkvT, EMBED, EMBED);
    tconv_kernel<<<dim3(EMBED / 32, EMBED / 32), blk, 0, stream>>>(Wk, WqkvT + (size_t)EMBED * EMBED, EMBED, EMBED);
    tconv_kernel<<<dim3(EMBED / 32, EMBED / 32), blk, 0, stream>>>(Wv, WqkvT + (size_t)2 * EMBED * EMBED, EMBED, EMBED);
    tconv_kernel<<<dim3(EMBED / 32, EMBED / 32), blk, 0, stream>>>(Wo, WoT, EMBED, EMBED);
    tconv_kernel<<<dim3(FFN_D / 32, EMBED / 32), blk, 0, stream>>>(W1, W1T, EMBED, FFN_D);
    tconv_kernel<<<dim3(EMBED / 32, FFN_D / 32), blk, 0, stream>>>(W2, W2T, FFN_D, EMBED);
    concat3_kernel<<<dim3(9), blk, 0, stream>>>(bq, bk, bv, bqkv);

    // LN1
    ln_kernel<<<dim3(TSEQ), blk, 0, stream>>>(x, ln1_g, ln1_b, hf, hh);
    // QKV fused GEMM
    gemm_kernel<0><<<dim3(CQKV / 128, TSEQ / 128), blk, 0, stream>>>(
        hh, WqkvT, bqkv, nullptr, nullptr, qkv, TSEQ, CQKV, EMBED);
    // V transpose for attention A-operand
    vtrans_kernel<<<dim3(TSEQ / 32, EMBED / 32), blk, 0, stream>>>(qkv, vT);
    // attention split-K partials + merge
    attn_kernel<<<dim3(NHEAD, TSEQ / 128, NSPLIT), blk, 0, stream>>>(qkv, vT, Opart, mlbuf);
    attn_merge_kernel<<<dim3(TSEQ), blk, 0, stream>>>(Opart, mlbuf, ctx);
    // Wo GEMM + residual(h)  (overwrites the Opart alias region - partials are dead)
    gemm_kernel<1><<<dim3(EMBED / 128, TSEQ / 128), blk, 0, stream>>>(
        ctx, WoT, bo, hf, x2, nullptr, TSEQ, EMBED, EMBED);
    // LN2
    ln_kernel<<<dim3(TSEQ), blk, 0, stream>>>(x2, ln2_g, ln2_b, h2f, h2h);
    // FFN1 + gelu
    gemm_kernel<2><<<dim3(FFN_D / 128, TSEQ / 128), blk, 0, stream>>>(
        h2h, W1T, b1, nullptr, nullptr, m1, TSEQ, FFN_D, EMBED);
    // FFN2 + residual(h2) -> fp32 out
    gemm_kernel<1><<<dim3(EMBED / 128, TSEQ / 128), blk, 0, stream>>>(
        m1, W2T, b2, h2f, (float*)d_out, nullptr, TSEQ, EMBED, FFN_D);
}

// Round 5
// 404.023 us; speedup vs baseline: 1.2282x; 1.2282x over previous
//
#include <hip/hip_runtime.h>
#include <math.h>

#define EMBED 768
#define FFN_D 3072
#define TSEQ 4096
#define NHEAD 12
#define DHEAD 64
#define CQKV 2304   // 3*EMBED
#define NSPLIT 4

typedef _Float16 f16;
typedef __attribute__((ext_vector_type(4))) _Float16 f16x4;
typedef __attribute__((ext_vector_type(8))) _Float16 f16x8;
typedef __attribute__((ext_vector_type(4))) float f32x4;

// async global->LDS, 16B per lane; lds base must be wave-uniform, lane i lands at base + i*16
__device__ __forceinline__ void gload16(const f16* g, f16* lds) {
    __builtin_amdgcn_global_load_lds((const __attribute__((address_space(1))) void*)g,
                                     (__attribute__((address_space(3))) void*)lds, 16, 0, 0);
}

// ---------------- transpose + fp32->fp16 convert: W[din][dout] -> WT[dout][din]
__global__ __launch_bounds__(256) void tconv_kernel(const float* __restrict__ W,
                                                    f16* __restrict__ WT,
                                                    int din, int dout) {
    __shared__ float tile[32][33];
    const int j0 = blockIdx.x * 32;   // dout
    const int i0 = blockIdx.y * 32;   // din
    const int tx = threadIdx.x & 31;
    const int ty = threadIdx.x >> 5;  // 0..7
#pragma unroll
    for (int rr = ty; rr < 32; rr += 8)
        tile[rr][tx] = W[(size_t)(i0 + rr) * dout + j0 + tx];
    __syncthreads();
#pragma unroll
    for (int rr = ty; rr < 32; rr += 8)
        WT[(size_t)(j0 + rr) * din + i0 + tx] = (f16)tile[tx][rr];
}

// ---------------- f16 transpose of the V section of qkv -> vT[h*64+d][t]
__global__ __launch_bounds__(256) void vtrans_kernel(const f16* __restrict__ qkv,
                                                     f16* __restrict__ vT) {
    __shared__ f16 tile[32][34];
    const int t0 = blockIdx.x * 32;   // seq
    const int c0 = blockIdx.y * 32;   // channel 0..767
    const int tx = threadIdx.x & 31;
    const int ty = threadIdx.x >> 5;
#pragma unroll
    for (int rr = ty; rr < 32; rr += 8)
        tile[rr][tx] = qkv[(size_t)(t0 + rr) * CQKV + 2 * EMBED + c0 + tx];
    __syncthreads();
#pragma unroll
    for (int rr = ty; rr < 32; rr += 8)
        vT[(size_t)(c0 + rr) * TSEQ + t0 + tx] = tile[tx][rr];
}

// ---------------- concat 3 bias vectors of 768 into [2304]
__global__ void concat3_kernel(const float* __restrict__ a, const float* __restrict__ b,
                               const float* __restrict__ c, float* __restrict__ o) {
    int i = blockIdx.x * 256 + threadIdx.x;
    if (i < 768) o[i] = a[i];
    else if (i < 1536) o[i] = b[i - 768];
    else if (i < 2304) o[i] = c[i - 1536];
}

// ---------------- LayerNorm row kernel (768 wide), writes f32 + f16
__global__ __launch_bounds__(256) void ln_kernel(const float* __restrict__ x,
                                                 const float* __restrict__ g,
                                                 const float* __restrict__ b,
                                                 float* __restrict__ hf,
                                                 f16* __restrict__ hh) {
    const int row = blockIdx.x;
    const float* xr = x + (size_t)row * EMBED;
    const int t = threadIdx.x;
    float v0 = xr[t], v1 = xr[t + 256], v2 = xr[t + 512];
    float s = v0 + v1 + v2;
#pragma unroll
    for (int m = 1; m < 64; m <<= 1) s += __shfl_xor(s, m);
    __shared__ float red[4], red2[4];
    const int wid = t >> 6, lane = t & 63;
    if (lane == 0) red[wid] = s;
    __syncthreads();
    float mean = (red[0] + red[1] + red[2] + red[3]) * (1.0f / 768.0f);
    float d0 = v0 - mean, d1 = v1 - mean, d2 = v2 - mean;
    float ss = d0 * d0 + d1 * d1 + d2 * d2;
#pragma unroll
    for (int m = 1; m < 64; m <<= 1) ss += __shfl_xor(ss, m);
    if (lane == 0) red2[wid] = ss;
    __syncthreads();
    float inv = rsqrtf((red2[0] + red2[1] + red2[2] + red2[3]) * (1.0f / 768.0f) + 1e-5f);
    float o0 = d0 * inv * g[t] + b[t];
    float o1 = d1 * inv * g[t + 256] + b[t + 256];
    float o2 = d2 * inv * g[t + 512] + b[t + 512];
    size_t base = (size_t)row * EMBED;
    hf[base + t] = o0; hf[base + t + 256] = o1; hf[base + t + 512] = o2;
    hh[base + t] = (f16)o0; hh[base + t + 256] = (f16)o1; hh[base + t + 512] = (f16)o2;
}

// ---------------- GEMM: C[M][N] = A[M][K] * BT[N][K]^T + bias, BM=128, BN in {128,64}
// EPI 0: out fp16    EPI 1: out fp32 = acc+bias+res    EPI 2: out fp16 = gelu(acc+bias)
template <int EPI, int BN>
__global__ __launch_bounds__(256) void gemm_kernel(const f16* __restrict__ A,
                                                   const f16* __restrict__ BT,
                                                   const float* __restrict__ bias,
                                                   const float* __restrict__ res,
                                                   float* __restrict__ outf,
                                                   f16* __restrict__ outh,
                                                   int M, int N, int K) {
    constexpr int JN = BN / 32;          // n-tiles of 16 per wave (4 or 2)
    constexpr int BROWS = BN / 4;        // B rows staged per wave
    __shared__ __align__(16) f16 As[128][32];
    __shared__ __align__(16) f16 Bs[BN][32];
    const int t = threadIdx.x;
    const int m0 = blockIdx.y * 128;
    const int n0 = blockIdx.x * BN;
    const int wid = t >> 6;
    const int lane = t & 63;
    const int wm = (wid >> 1) * 64;
    const int wn = (wid & 1) * (BN / 2);
    const int lr = lane & 15;
    const int lk = (lane >> 4) * 8;
    const int srow = lane >> 2;        // 0..15 within a 16-row DMA call
    const int scol = (lane & 3) * 8;   // k-offset within call

    f32x4 zero = {0.f, 0.f, 0.f, 0.f};
    f32x4 acc[4][JN];
#pragma unroll
    for (int i = 0; i < 4; i++)
#pragma unroll
        for (int j = 0; j < JN; j++) acc[i][j] = zero;

    const f16* Ap = A + (size_t)(m0 + wid * 32 + srow) * K + scol;
    const f16* Bp = BT + (size_t)(n0 + wid * BROWS + srow) * K + scol;

    for (int k0 = 0; k0 < K; k0 += 32) {
        __syncthreads();
        gload16(Ap + k0, &As[wid * 32][0]);
        gload16(Ap + (size_t)16 * K + k0, &As[wid * 32 + 16][0]);
#pragma unroll
        for (int c = 0; c < BROWS / 16; c++)
            gload16(Bp + (size_t)(c * 16) * K + k0, &Bs[wid * BROWS + c * 16][0]);
        __syncthreads();
        f16x8 af[4], bf[JN];
#pragma unroll
        for (int i = 0; i < 4; i++) af[i] = *(const f16x8*)&As[wm + i * 16 + lr][lk];
#pragma unroll
        for (int j = 0; j < JN; j++) bf[j] = *(const f16x8*)&Bs[wn + j * 16 + lr][lk];
#pragma unroll
        for (int i = 0; i < 4; i++)
#pragma unroll
            for (int j = 0; j < JN; j++)
                acc[i][j] = __builtin_amdgcn_mfma_f32_16x16x32_f16(af[i], bf[j], acc[i][j], 0, 0, 0);
    }

    const int q4 = (lane >> 4) * 4;
#pragma unroll
    for (int i = 0; i < 4; i++) {
        const int row = m0 + wm + i * 16 + q4;
#pragma unroll
        for (int j = 0; j < JN; j++) {
            const int col = n0 + wn + j * 16 + lr;
            const float bv = bias[col];
#pragma unroll
            for (int r = 0; r < 4; r++) {
                float v = acc[i][j][r] + bv;
                size_t idx = (size_t)(row + r) * N + col;
                if (EPI == 0) {
                    outh[idx] = (f16)v;
                } else if (EPI == 1) {
                    outf[idx] = v + res[idx];
                } else {
                    float gl = 0.5f * v * (1.0f + erff(v * 0.70710678118654752f));
                    outh[idx] = (f16)gl;
                }
            }
        }
    }
}

// ---------------- flash attention: LDS-staged K/V^T + S^T register orientation
// S^T = mfma(A=K, B=Q); P^T exits in B-operand layout (k-dim permuted, matched by
// V^T A-frags) so PV needs no LDS round-trip. 2 barriers/tile, 18.4 KB LDS.
// Opart: [NSPLIT][TSEQ][768] fp32 unnormalized O. ml: [NSPLIT][TSEQ][NHEAD] (m,l)
__global__ __launch_bounds__(256) void attn_kernel(const f16* __restrict__ qkv,
                                                   const f16* __restrict__ vT,
                                                   float* __restrict__ Opart,
                                                   float2* __restrict__ ml) {
    __shared__ __align__(16) f16 Ks[64][72];   // [key][d]
    __shared__ __align__(16) f16 Vt[64][72];   // [d][key]
    const int h  = blockIdx.x;                    // 0..11
    const int qb = (gridDim.y - 1) - blockIdx.y;  // longest blocks dispatched first
    const int sp = blockIdx.z;
    const int q0 = qb * 128;
    const int t = threadIdx.x;
    const int wid = t >> 6;
    const int lane = t & 63;
    const int lr = lane & 15;
    const int quad = lane >> 4;
    const int srow = t >> 3;        // 0..31 (staging)
    const int scol = (t & 7) * 8;   // 0..56

    const int nkb = 2 * qb + 2;
    const int chunk = (nkb + NSPLIT - 1) / NSPLIT;
    const int kb0 = sp * chunk;
    const int kb1 = min(nkb, kb0 + chunk);
    const int wrow0 = q0 + wid * 32;              // first q-row of this wave
    const float sc2 = 0.125f * 1.4426950408889634f;   // 1/sqrt(64) * log2(e)

    // loop-invariant Q fragments (B-operand: n = q = qt*16+lr, k = d = dh*32+quad*8+e)
    f16x8 qf[2][2];
#pragma unroll
    for (int qt = 0; qt < 2; qt++)
#pragma unroll
        for (int dh = 0; dh < 2; dh++)
            qf[qt][dh] = *(const f16x8*)(qkv + (size_t)(wrow0 + qt * 16 + lr) * CQKV
                                         + h * DHEAD + dh * 32 + quad * 8);

    float m_i[2] = {-INFINITY, -INFINITY};
    float l_i[2] = {0.f, 0.f};
    f32x4 zero = {0.f, 0.f, 0.f, 0.f};
    f32x4 o[4][2];   // O^T tiles: [dt][qt], d = dt*16+quad*4+r, q = qt*16+lr
#pragma unroll
    for (int dt = 0; dt < 4; dt++)
#pragma unroll
        for (int qt = 0; qt < 2; qt++) o[dt][qt] = zero;

    // register prefetch of K/V tile kb0
    int4 kreg[2], vreg[2];
    const f16* kbase = qkv + EMBED + (size_t)h * DHEAD;
    const f16* vbase = vT + (size_t)h * DHEAD * TSEQ;
    if (kb0 < kb1) {
        const int k0 = kb0 * 64;
#pragma unroll
        for (int p = 0; p < 2; p++) {
            kreg[p] = *(const int4*)(kbase + (size_t)(k0 + p * 32 + srow) * CQKV + scol);
            vreg[p] = *(const int4*)(vbase + (size_t)(p * 32 + srow) * TSEQ + k0 + scol);
        }
    }

    for (int kb = kb0; kb < kb1; ++kb) {
        const int k0 = kb * 64;
        __syncthreads();   // prior iteration's fragment reads done
#pragma unroll
        for (int p = 0; p < 2; p++) {
            *(int4*)&Ks[p * 32 + srow][scol] = kreg[p];
            *(int4*)&Vt[p * 32 + srow][scol] = vreg[p];
        }
        __syncthreads();
        if (kb + 1 < kb1) {   // prefetch next tile (overlaps compute)
            const int kn = (kb + 1) * 64;
#pragma unroll
            for (int p = 0; p < 2; p++) {
                kreg[p] = *(const int4*)(kbase + (size_t)(kn + p * 32 + srow) * CQKV + scol);
                vreg[p] = *(const int4*)(vbase + (size_t)(p * 32 + srow) * TSEQ + kn + scol);
            }
        }

        if (k0 <= wrow0 + 31) {   // wave-uniform compute guard (barriers always hit)
            // S^T[key][q] per wave: 64 keys x 32 q
            f32x4 s[4][2];
#pragma unroll
            for (int kt = 0; kt < 4; kt++)
#pragma unroll
                for (int qt = 0; qt < 2; qt++) s[kt][qt] = zero;
#pragma unroll
            for (int dh = 0; dh < 2; dh++) {
#pragma unroll
                for (int kt = 0; kt < 4; kt++) {
                    f16x8 kf = *(const f16x8*)&Ks[kt * 16 + lr][dh * 32 + quad * 8];
#pragma unroll
                    for (int qt = 0; qt < 2; qt++)
                        s[kt][qt] = __builtin_amdgcn_mfma_f32_16x16x32_f16(kf, qf[qt][dh], s[kt][qt], 0, 0, 0);
                }
            }

            // scale into log2 domain (+ causal mask only on boundary tiles)
            if (k0 + 63 > wrow0) {
#pragma unroll
                for (int kt = 0; kt < 4; kt++)
#pragma unroll
                    for (int qt = 0; qt < 2; qt++)
#pragma unroll
                        for (int r = 0; r < 4; r++) {
                            int key = k0 + kt * 16 + quad * 4 + r;
                            int row = wrow0 + qt * 16 + lr;
                            float v = s[kt][qt][r] * sc2;
                            s[kt][qt][r] = (key > row) ? -INFINITY : v;
                        }
            } else {
#pragma unroll
                for (int kt = 0; kt < 4; kt++)
#pragma unroll
                    for (int qt = 0; qt < 2; qt++)
#pragma unroll
                        for (int r = 0; r < 4; r++) s[kt][qt][r] *= sc2;
            }

            // online softmax per q-row (qt,lr): 16 in-reg + 2 cross-quad shuffles
            float al[2];
#pragma unroll
            for (int qt = 0; qt < 2; qt++) {
                float mx = -INFINITY;
#pragma unroll
                for (int kt = 0; kt < 4; kt++)
#pragma unroll
                    for (int r = 0; r < 4; r++) mx = fmaxf(mx, s[kt][qt][r]);
                mx = fmaxf(mx, __shfl_xor(mx, 16));
                mx = fmaxf(mx, __shfl_xor(mx, 32));
                float mn = fmaxf(m_i[qt], mx);
                al[qt] = exp2f(m_i[qt] - mn);   // 0 on first visit
                m_i[qt] = mn;
            }
            // P^T = 2^(s-m), packed directly into PV B-frags (k-permuted)
            float rs[2] = {0.f, 0.f};
            f16x8 pf[2][2];   // [kstep][qt]
#pragma unroll
            for (int kt = 0; kt < 4; kt++)
#pragma unroll
                for (int qt = 0; qt < 2; qt++)
#pragma unroll
                    for (int r = 0; r < 4; r++) {
                        float pe = exp2f(s[kt][qt][r] - m_i[qt]);
                        rs[qt] += pe;
                        pf[kt >> 1][qt][(kt & 1) * 4 + r] = (f16)pe;
                    }
#pragma unroll
            for (int qt = 0; qt < 2; qt++) {
                float v = rs[qt];
                v += __shfl_xor(v, 16);
                v += __shfl_xor(v, 32);
                l_i[qt] = l_i[qt] * al[qt] + v;
            }
            // rescale O^T, then O^T += V^T @ P^T
#pragma unroll
            for (int dt = 0; dt < 4; dt++)
#pragma unroll
                for (int qt = 0; qt < 2; qt++)
#pragma unroll
                    for (int r = 0; r < 4; r++) o[dt][qt][r] *= al[qt];
#pragma unroll
            for (int s2 = 0; s2 < 2; s2++)
#pragma unroll
                for (int dt = 0; dt < 4; dt++) {
                    // A-frag: m = d = dt*16+lr; k-perm key = s2*32 + (e>>2)*16 + quad*4 + (e&3)
                    f16x4 vlo = *(const f16x4*)&Vt[dt * 16 + lr][s2 * 32 + quad * 4];
                    f16x4 vhi = *(const f16x4*)&Vt[dt * 16 + lr][s2 * 32 + quad * 4 + 16];
                    f16x8 vf;
#pragma unroll
                    for (int e = 0; e < 4; e++) { vf[e] = vlo[e]; vf[e + 4] = vhi[e]; }
#pragma unroll
                    for (int qt = 0; qt < 2; qt++)
                        o[dt][qt] = __builtin_amdgcn_mfma_f32_16x16x32_f16(vf, pf[s2][qt], o[dt][qt], 0, 0, 0);
                }
        }
    }

    // store partials: O^T tile (dt,qt) reg r = contiguous d -> 16B vector stores
#pragma unroll
    for (int dt = 0; dt < 4; dt++)
#pragma unroll
        for (int qt = 0; qt < 2; qt++) {
            int row = wrow0 + qt * 16 + lr;
            float* dst = Opart + ((size_t)sp * TSEQ + row) * EMBED + h * DHEAD + dt * 16 + quad * 4;
            *(f32x4*)dst = o[dt][qt];
        }
#pragma unroll
    for (int qt = 0; qt < 2; qt++)
        if (quad == 0) {
            int row = wrow0 + qt * 16 + lr;
            ml[((size_t)sp * TSEQ + row) * NHEAD + h] = make_float2(m_i[qt], l_i[qt]);
        }
}

// ---------------- merge split-K partials -> ctx f16
__global__ __launch_bounds__(256) void attn_merge_kernel(const float* __restrict__ Opart,
                                                         const float2* __restrict__ ml,
                                                         f16* __restrict__ ctx) {
    const int row = blockIdx.x;
    const int t = threadIdx.x;
    __shared__ float wgt[NSPLIT][NHEAD];
    if (t < NHEAD) {
        float m[NSPLIT], l[NSPLIT];
        float M = -INFINITY;
#pragma unroll
        for (int s = 0; s < NSPLIT; s++) {
            float2 v = ml[((size_t)s * TSEQ + row) * NHEAD + t];
            m[s] = v.x; l[s] = v.y;
            M = fmaxf(M, m[s]);
        }
        float L = 0.f;
        float w[NSPLIT];
#pragma unroll
        for (int s = 0; s < NSPLIT; s++) {
            w[s] = exp2f(m[s] - M);
            L += l[s] * w[s];
        }
        float rL = 1.0f / L;
#pragma unroll
        for (int s = 0; s < NSPLIT; s++) wgt[s][t] = w[s] * rL;
    }
    __syncthreads();
#pragma unroll
    for (int p = 0; p < 3; p++) {
        int c = t + p * 256;
        int h = c >> 6;
        float acc = 0.f;
#pragma unroll
        for (int s = 0; s < NSPLIT; s++)
            acc += wgt[s][h] * Opart[((size_t)s * TSEQ + row) * EMBED + c];
        ctx[(size_t)row * EMBED + c] = (f16)acc;
    }
}

extern "C" void kernel_launch(void* const* d_in, const int* in_sizes, int n_in,
                              void* d_out, int out_size, void* d_ws, size_t ws_size,
                              hipStream_t stream) {
    const float* x     = (const float*)d_in[0];
    const float* Wq    = (const float*)d_in[1];
    const float* bq    = (const float*)d_in[2];
    const float* Wk    = (const float*)d_in[3];
    const float* bk    = (const float*)d_in[4];
    const float* Wv    = (const float*)d_in[5];
    const float* bv    = (const float*)d_in[6];
    const float* Wo    = (const float*)d_in[7];
    const float* bo    = (const float*)d_in[8];
    const float* ln1_g = (const float*)d_in[9];
    const float* ln1_b = (const float*)d_in[10];
    const float* ln2_g = (const float*)d_in[11];
    const float* ln2_b = (const float*)d_in[12];
    const float* W1    = (const float*)d_in[13];
    const float* b1    = (const float*)d_in[14];
    const float* W2    = (const float*)d_in[15];
    const float* b2    = (const float*)d_in[16];

    char* p = (char*)d_ws;
    auto alloc = [&](size_t bytes) -> void* {
        void* r = (void*)p;
        p += (bytes + 255) & ~(size_t)255;
        return r;
    };
    f16*   WqkvT = (f16*)alloc((size_t)CQKV * EMBED * 2);   // [2304][768]
    f16*   WoT   = (f16*)alloc((size_t)EMBED * EMBED * 2);  // [768][768]
    f16*   W1T   = (f16*)alloc((size_t)FFN_D * EMBED * 2);  // [3072][768]
    f16*   W2T   = (f16*)alloc((size_t)EMBED * FFN_D * 2);  // [768][3072]
    float* bqkv  = (float*)alloc((size_t)CQKV * 4);
    float* hf    = (float*)alloc((size_t)TSEQ * EMBED * 4);
    f16*   hh    = (f16*)alloc((size_t)TSEQ * EMBED * 2);
    f16*   qkv   = (f16*)alloc((size_t)TSEQ * CQKV * 2);
    f16*   vT    = (f16*)alloc((size_t)EMBED * TSEQ * 2);   // [h*64+d][t]
    f16*   ctx   = (f16*)alloc((size_t)TSEQ * EMBED * 2);
    float* x2    = (float*)alloc((size_t)TSEQ * EMBED * 4);
    float* h2f   = (float*)alloc((size_t)TSEQ * EMBED * 4);
    f16*   h2h   = (f16*)alloc((size_t)TSEQ * EMBED * 2);
    f16*   m1    = (f16*)alloc((size_t)TSEQ * FFN_D * 2);

    // split-K attention partials ALIAS the post-attention buffers (x2..m1 span
    // 56.7 MB >= 50.3+1.6 MB; attention+merge complete before x2 is written)
    float*  Opart = x2;                                        // [NSPLIT][TSEQ][768] f32
    float2* mlbuf = (float2*)(x2 + (size_t)NSPLIT * TSEQ * EMBED);

    dim3 blk(256);
    tconv_kernel<<<dim3(EMBED / 32, EMBED / 32), blk, 0, stream>>>(Wq, WqkvT, EMBED, EMBED);
    tconv_kernel<<<dim3(EMBED / 32, EMBED / 32), blk, 0, stream>>>(Wk, WqkvT + (size_t)EMBED * EMBED, EMBED, EMBED);
    tconv_kernel<<<dim3(EMBED / 32, EMBED / 32), blk, 0, stream>>>(Wv, WqkvT + (size_t)2 * EMBED * EMBED, EMBED, EMBED);
    tconv_kernel<<<dim3(EMBED / 32, EMBED / 32), blk, 0, stream>>>(Wo, WoT, EMBED, EMBED);
    tconv_kernel<<<dim3(FFN_D / 32, EMBED / 32), blk, 0, stream>>>(W1, W1T, EMBED, FFN_D);
    tconv_kernel<<<dim3(EMBED / 32, FFN_D / 32), blk, 0, stream>>>(W2, W2T, FFN_D, EMBED);
    concat3_kernel<<<dim3(9), blk, 0, stream>>>(bq, bk, bv, bqkv);

    // LN1
    ln_kernel<<<dim3(TSEQ), blk, 0, stream>>>(x, ln1_g, ln1_b, hf, hh);
    // QKV fused GEMM
    gemm_kernel<0, 128><<<dim3(CQKV / 128, TSEQ / 128), blk, 0, stream>>>(
        hh, WqkvT, bqkv, nullptr, nullptr, qkv, TSEQ, CQKV, EMBED);
    // V transpose for attention A-operand
    vtrans_kernel<<<dim3(TSEQ / 32, EMBED / 32), blk, 0, stream>>>(qkv, vT);
    // attention split-K partials + merge
    attn_kernel<<<dim3(NHEAD, TSEQ / 128, NSPLIT), blk, 0, stream>>>(qkv, vT, Opart, mlbuf);
    attn_merge_kernel<<<dim3(TSEQ), blk, 0, stream>>>(Opart, mlbuf, ctx);
    // Wo GEMM + residual(h)  (overwrites the Opart alias region - partials are dead)
    gemm_kernel<1, 64><<<dim3(EMBED / 64, TSEQ / 128), blk, 0, stream>>>(
        ctx, WoT, bo, hf, x2, nullptr, TSEQ, EMBED, EMBED);
    // LN2
    ln_kernel<<<dim3(TSEQ), blk, 0, stream>>>(x2, ln2_g, ln2_b, h2f, h2h);
    // FFN1 + gelu
    gemm_kernel<2, 128><<<dim3(FFN_D / 128, TSEQ / 128), blk, 0, stream>>>(
        h2h, W1T, b1, nullptr, nullptr, m1, TSEQ, FFN_D, EMBED);
    // FFN2 + residual(h2) -> fp32 out
    gemm_kernel<1, 64><<<dim3(EMBED / 64, TSEQ / 128), blk, 0, stream>>>(
        m1, W2T, b2, h2f, (float*)d_out, nullptr, TSEQ, EMBED, FFN_D);
}

// Round 7
// 400.868 us; speedup vs baseline: 1.2378x; 1.0079x over previous
//
#include <hip/hip_runtime.h>
#include <math.h>

#define EMBED 768
#define FFN_D 3072
#define TSEQ 4096
#define NHEAD 12
#define DHEAD 64
#define CQKV 2304   // 3*EMBED
#define NSPLIT 4
#define NITEMS (32 * NHEAD * NSPLIT)   // (TSEQ/128) * heads * splits
#define SC2Q 0.180336880111120419f     // 0.125 * log2(e), folded into Q in QKV epilogue

typedef _Float16 f16;
typedef __attribute__((ext_vector_type(2))) _Float16 f16x2;
typedef __attribute__((ext_vector_type(4))) _Float16 f16x4;
typedef __attribute__((ext_vector_type(8))) _Float16 f16x8;
typedef __attribute__((ext_vector_type(4))) float f32x4;

__device__ __forceinline__ f16x2 pkrtz(float a, float b) {
    return __builtin_bit_cast(f16x2, __builtin_amdgcn_cvt_pkrtz(a, b));
}

// async global->LDS, 16B per lane; lds base wave-uniform, lane i lands at base + i*16
__device__ __forceinline__ void gload16(const f16* g, f16* lds) {
    __builtin_amdgcn_global_load_lds((const __attribute__((address_space(1))) void*)g,
                                     (__attribute__((address_space(3))) void*)lds, 16, 0, 0);
}

// ---------------- transpose + fp32->fp16 convert: W[din][dout] -> WT[dout][din]
__global__ __launch_bounds__(256) void tconv_kernel(const float* __restrict__ W,
                                                    f16* __restrict__ WT,
                                                    int din, int dout) {
    __shared__ float tile[32][33];
    const int j0 = blockIdx.x * 32;
    const int i0 = blockIdx.y * 32;
    const int tx = threadIdx.x & 31;
    const int ty = threadIdx.x >> 5;
#pragma unroll
    for (int rr = ty; rr < 32; rr += 8)
        tile[rr][tx] = W[(size_t)(i0 + rr) * dout + j0 + tx];
    __syncthreads();
#pragma unroll
    for (int rr = ty; rr < 32; rr += 8)
        WT[(size_t)(j0 + rr) * din + i0 + tx] = (f16)tile[tx][rr];
}

// ---------------- f16 transpose of the V section of qkv -> vT[h*64+d][t]
__global__ __launch_bounds__(256) void vtrans_kernel(const f16* __restrict__ qkv,
                                                     f16* __restrict__ vT) {
    __shared__ f16 tile[32][34];
    const int t0 = blockIdx.x * 32;
    const int c0 = blockIdx.y * 32;
    const int tx = threadIdx.x & 31;
    const int ty = threadIdx.x >> 5;
#pragma unroll
    for (int rr = ty; rr < 32; rr += 8)
        tile[rr][tx] = qkv[(size_t)(t0 + rr) * CQKV + 2 * EMBED + c0 + tx];
    __syncthreads();
#pragma unroll
    for (int rr = ty; rr < 32; rr += 8)
        vT[(size_t)(c0 + rr) * TSEQ + t0 + tx] = tile[tx][rr];
}

// ---------------- concat 3 bias vectors of 768 into [2304]
__global__ void concat3_kernel(const float* __restrict__ a, const float* __restrict__ b,
                               const float* __restrict__ c, float* __restrict__ o) {
    int i = blockIdx.x * 256 + threadIdx.x;
    if (i < 768) o[i] = a[i];
    else if (i < 1536) o[i] = b[i - 768];
    else if (i < 2304) o[i] = c[i - 1536];
}

// ---------------- LayerNorm row kernel (768 wide), writes f32 + f16
__global__ __launch_bounds__(256) void ln_kernel(const float* __restrict__ x,
                                                 const float* __restrict__ g,
                                                 const float* __restrict__ b,
                                                 float* __restrict__ hf,
                                                 f16* __restrict__ hh) {
    const int row = blockIdx.x;
    const float* xr = x + (size_t)row * EMBED;
    const int t = threadIdx.x;
    float v0 = xr[t], v1 = xr[t + 256], v2 = xr[t + 512];
    float s = v0 + v1 + v2;
#pragma unroll
    for (int m = 1; m < 64; m <<= 1) s += __shfl_xor(s, m);
    __shared__ float red[4], red2[4];
    const int wid = t >> 6, lane = t & 63;
    if (lane == 0) red[wid] = s;
    __syncthreads();
    float mean = (red[0] + red[1] + red[2] + red[3]) * (1.0f / 768.0f);
    float d0 = v0 - mean, d1 = v1 - mean, d2 = v2 - mean;
    float ss = d0 * d0 + d1 * d1 + d2 * d2;
#pragma unroll
    for (int m = 1; m < 64; m <<= 1) ss += __shfl_xor(ss, m);
    if (lane == 0) red2[wid] = ss;
    __syncthreads();
    float inv = rsqrtf((red2[0] + red2[1] + red2[2] + red2[3]) * (1.0f / 768.0f) + 1e-5f);
    float o0 = d0 * inv * g[t] + b[t];
    float o1 = d1 * inv * g[t + 256] + b[t + 256];
    float o2 = d2 * inv * g[t + 512] + b[t + 512];
    size_t base = (size_t)row * EMBED;
    hf[base + t] = o0; hf[base + t + 256] = o1; hf[base + t + 512] = o2;
    hh[base + t] = (f16)o0; hh[base + t + 256] = (f16)o1; hh[base + t + 512] = (f16)o2;
}

// ---------------- GEMM: C[M][N] = A[M][K] * BT[N][K]^T + bias
// BK=64, XOR-swizzled LDS (chunk ^ row&7) to keep b128 frag reads ~conflict-free while
// preserving global_load_lds deposit contiguity. MFMA operands SWAPPED so acc reg r spans
// 4 consecutive output columns -> fully vectorized epilogue (float4 bias/res, 16B stores).
// EPI 0: out fp16 (QKV: cols<768 scaled by SC2Q)  EPI 1: fp32 acc+bias+res  EPI 2: fp16 gelu
template <int EPI, int BN>
__global__ __launch_bounds__(256) void gemm_kernel(const f16* __restrict__ A,
                                                   const f16* __restrict__ BT,
                                                   const float* __restrict__ bias,
                                                   const float* __restrict__ res,
                                                   float* __restrict__ outf,
                                                   f16* __restrict__ outh,
                                                   int M, int N, int K) {
    constexpr int JN = BN / 32;
    constexpr int BROWS = BN / 4;
    __shared__ __align__(16) f16 As[128][64];
    __shared__ __align__(16) f16 Bs[BN][64];
    const int t = threadIdx.x;
    const int m0 = blockIdx.y * 128;
    const int n0 = blockIdx.x * BN;
    const int wid = t >> 6;
    const int lane = t & 63;
    const int wm = (wid >> 1) * 64;
    const int wn = (wid & 1) * (BN / 2);
    const int lr = lane & 15;
    const int quad = lane >> 4;
    const int sr = lane >> 3;            // 0..7 (row within an 8-row DMA call)
    const int scn = (lane & 7) ^ sr;     // swizzled source chunk (8 f16 per chunk)
    const int xv = lr & 7;               // read-side xor

    f32x4 zero = {0.f, 0.f, 0.f, 0.f};
    f32x4 acc[4][JN];
#pragma unroll
    for (int i = 0; i < 4; i++)
#pragma unroll
        for (int j = 0; j < JN; j++) acc[i][j] = zero;

    const f16* Ap = A + (size_t)(m0 + wid * 32 + sr) * K + scn * 8;
    const f16* Bp = BT + (size_t)(n0 + wid * BROWS + sr) * K + scn * 8;

    for (int k0 = 0; k0 < K; k0 += 64) {
        __syncthreads();
#pragma unroll
        for (int c = 0; c < 4; c++)
            gload16(Ap + (size_t)(c * 8) * K + k0, &As[wid * 32 + c * 8][0]);
#pragma unroll
        for (int c = 0; c < BROWS / 8; c++)
            gload16(Bp + (size_t)(c * 8) * K + k0, &Bs[wid * BROWS + c * 8][0]);
        __syncthreads();
#pragma unroll
        for (int ks = 0; ks < 2; ks++) {
            f16x8 af[4], bf[JN];
#pragma unroll
            for (int i = 0; i < 4; i++)
                af[i] = *(const f16x8*)&As[wm + i * 16 + lr][((ks * 4 + quad) ^ xv) * 8];
#pragma unroll
            for (int j = 0; j < JN; j++)
                bf[j] = *(const f16x8*)&Bs[wn + j * 16 + lr][((ks * 4 + quad) ^ xv) * 8];
#pragma unroll
            for (int i = 0; i < 4; i++)
#pragma unroll
                for (int j = 0; j < JN; j++)
                    acc[i][j] = __builtin_amdgcn_mfma_f32_16x16x32_f16(bf[j], af[i], acc[i][j], 0, 0, 0);
        }
    }

    // acc[i][j][r] = C[row = m0+wm+i*16+lr][col = n0+wn+j*16+quad*4+r]
#pragma unroll
    for (int i = 0; i < 4; i++) {
        const int row = m0 + wm + i * 16 + lr;
#pragma unroll
        for (int j = 0; j < JN; j++) {
            const int col = n0 + wn + j * 16 + quad * 4;
            const float4 bv = *(const float4*)&bias[col];
            float v0 = acc[i][j][0] + bv.x;
            float v1 = acc[i][j][1] + bv.y;
            float v2 = acc[i][j][2] + bv.z;
            float v3 = acc[i][j][3] + bv.w;
            const size_t idx = (size_t)row * N + col;
            if (EPI == 0) {
                const float qs = (col < EMBED) ? SC2Q : 1.0f;
                f16x4 hv = {(f16)(v0 * qs), (f16)(v1 * qs), (f16)(v2 * qs), (f16)(v3 * qs)};
                *(f16x4*)&outh[idx] = hv;
            } else if (EPI == 1) {
                const float4 rr = *(const float4*)&res[idx];
                f32x4 ov = {v0 + rr.x, v1 + rr.y, v2 + rr.z, v3 + rr.w};
                *(f32x4*)&outf[idx] = ov;
            } else {
                f16x4 hv = {(f16)(0.5f * v0 * (1.0f + erff(v0 * 0.70710678118654752f))),
                            (f16)(0.5f * v1 * (1.0f + erff(v1 * 0.70710678118654752f))),
                            (f16)(0.5f * v2 * (1.0f + erff(v2 * 0.70710678118654752f))),
                            (f16)(0.5f * v3 * (1.0f + erff(v3 * 0.70710678118654752f)))};
                *(f16x4*)&outh[idx] = hv;
            }
        }
    }
}

// ---------------- persistent flash attention: atomic work queue over (qb desc, h, sp)
// LDS-staged K/V^T + S^T register orientation; P^T packed straight into PV B-frags.
// Q pre-scaled by SC2Q in the QKV epilogue (scores already log2-domain).
__global__ __launch_bounds__(256) void attn_kernel(const f16* __restrict__ qkv,
                                                   const f16* __restrict__ vT,
                                                   float* __restrict__ Opart,
                                                   float2* __restrict__ ml,
                                                   int* __restrict__ ctr) {
    __shared__ __align__(16) f16 Ks[64][72];   // [key][d]
    __shared__ __align__(16) f16 Vt[64][72];   // [d][key]
    __shared__ int s_item;
    const int t = threadIdx.x;
    const int wid = t >> 6;
    const int lane = t & 63;
    const int lr = lane & 15;
    const int quad = lane >> 4;
    const int srow = t >> 3;        // 0..31 (staging)
    const int scol = (t & 7) * 8;   // 0..56

    for (;;) {
        __syncthreads();
        if (t == 0) s_item = atomicAdd(ctr, 1);
        __syncthreads();
        const int item = s_item;
        if (item >= NITEMS) return;
        const int qb = 31 - item / (NHEAD * NSPLIT);
        const int rem = item % (NHEAD * NSPLIT);
        const int h = rem >> 2;
        const int sp = rem & 3;
        const int q0 = qb * 128;

        const int nkb = 2 * qb + 2;
        const int chunk = (nkb + NSPLIT - 1) / NSPLIT;
        const int kb0 = sp * chunk;
        const int kb1 = min(nkb, kb0 + chunk);
        const int wrow0 = q0 + wid * 32;

        float m_i[2] = {-INFINITY, -INFINITY};
        float l_lane[2] = {0.f, 0.f};           // per-lane partial sums (reduced at item end)
        f32x4 zero = {0.f, 0.f, 0.f, 0.f};
        f32x4 o[4][2];
#pragma unroll
        for (int dt = 0; dt < 4; dt++)
#pragma unroll
            for (int qt = 0; qt < 2; qt++) o[dt][qt] = zero;

        f16x8 qf[2][2];
        int4 kreg[2], vreg[2];
        const f16* kbase = qkv + EMBED + (size_t)h * DHEAD;
        const f16* vbase = vT + (size_t)h * DHEAD * TSEQ;
        if (kb0 < kb1) {
#pragma unroll
            for (int qt = 0; qt < 2; qt++)
#pragma unroll
                for (int dh = 0; dh < 2; dh++)
                    qf[qt][dh] = *(const f16x8*)(qkv + (size_t)(wrow0 + qt * 16 + lr) * CQKV
                                                 + h * DHEAD + dh * 32 + quad * 8);
            const int k0 = kb0 * 64;
#pragma unroll
            for (int p = 0; p < 2; p++) {
                kreg[p] = *(const int4*)(kbase + (size_t)(k0 + p * 32 + srow) * CQKV + scol);
                vreg[p] = *(const int4*)(vbase + (size_t)(p * 32 + srow) * TSEQ + k0 + scol);
            }
        }

        for (int kb = kb0; kb < kb1; ++kb) {
            const int k0 = kb * 64;
            __syncthreads();
#pragma unroll
            for (int p = 0; p < 2; p++) {
                *(int4*)&Ks[p * 32 + srow][scol] = kreg[p];
                *(int4*)&Vt[p * 32 + srow][scol] = vreg[p];
            }
            __syncthreads();
            if (kb + 1 < kb1) {
                const int kn = (kb + 1) * 64;
#pragma unroll
                for (int p = 0; p < 2; p++) {
                    kreg[p] = *(const int4*)(kbase + (size_t)(kn + p * 32 + srow) * CQKV + scol);
                    vreg[p] = *(const int4*)(vbase + (size_t)(p * 32 + srow) * TSEQ + kn + scol);
                }
            }

            if (k0 <= wrow0 + 31) {   // wave-uniform compute guard (barriers always hit)
                f32x4 s[4][2];
#pragma unroll
                for (int kt = 0; kt < 4; kt++)
#pragma unroll
                    for (int qt = 0; qt < 2; qt++) s[kt][qt] = zero;
#pragma unroll
                for (int dh = 0; dh < 2; dh++) {
#pragma unroll
                    for (int kt = 0; kt < 4; kt++) {
                        f16x8 kf = *(const f16x8*)&Ks[kt * 16 + lr][dh * 32 + quad * 8];
#pragma unroll
                        for (int qt = 0; qt < 2; qt++)
                            s[kt][qt] = __builtin_amdgcn_mfma_f32_16x16x32_f16(kf, qf[qt][dh], s[kt][qt], 0, 0, 0);
                    }
                }
                // causal mask only on boundary tiles (s already scaled/log2-domain)
                if (k0 + 63 > wrow0) {
#pragma unroll
                    for (int kt = 0; kt < 4; kt++)
#pragma unroll
                        for (int qt = 0; qt < 2; qt++)
#pragma unroll
                            for (int r = 0; r < 4; r++) {
                                int key = k0 + kt * 16 + quad * 4 + r;
                                int row = wrow0 + qt * 16 + lr;
                                if (key > row) s[kt][qt][r] = -INFINITY;
                            }
                }
                float al[2];
#pragma unroll
                for (int qt = 0; qt < 2; qt++) {
                    float mx = -INFINITY;
#pragma unroll
                    for (int kt = 0; kt < 4; kt++)
#pragma unroll
                        for (int r = 0; r < 4; r++) mx = fmaxf(mx, s[kt][qt][r]);
                    mx = fmaxf(mx, __shfl_xor(mx, 16));
                    mx = fmaxf(mx, __shfl_xor(mx, 32));
                    float mn = fmaxf(m_i[qt], mx);
                    al[qt] = exp2f(m_i[qt] - mn);
                    m_i[qt] = mn;
                }
                union PW { f16x8 v8; f16x2 h2[4]; };
                PW pw[2][2];
                float rs[2] = {0.f, 0.f};
#pragma unroll
                for (int kt = 0; kt < 4; kt++)
#pragma unroll
                    for (int qt = 0; qt < 2; qt++) {
                        float p0 = exp2f(s[kt][qt][0] - m_i[qt]);
                        float p1 = exp2f(s[kt][qt][1] - m_i[qt]);
                        float p2 = exp2f(s[kt][qt][2] - m_i[qt]);
                        float p3 = exp2f(s[kt][qt][3] - m_i[qt]);
                        rs[qt] += (p0 + p1) + (p2 + p3);
                        pw[kt >> 1][qt].h2[(kt & 1) * 2]     = pkrtz(p0, p1);
                        pw[kt >> 1][qt].h2[(kt & 1) * 2 + 1] = pkrtz(p2, p3);
                    }
#pragma unroll
                for (int qt = 0; qt < 2; qt++) l_lane[qt] = l_lane[qt] * al[qt] + rs[qt];
#pragma unroll
                for (int dt = 0; dt < 4; dt++)
#pragma unroll
                    for (int qt = 0; qt < 2; qt++)
#pragma unroll
                        for (int r = 0; r < 4; r++) o[dt][qt][r] *= al[qt];
#pragma unroll
                for (int s2 = 0; s2 < 2; s2++)
#pragma unroll
                    for (int dt = 0; dt < 4; dt++) {
                        f16x4 vlo = *(const f16x4*)&Vt[dt * 16 + lr][s2 * 32 + quad * 4];
                        f16x4 vhi = *(const f16x4*)&Vt[dt * 16 + lr][s2 * 32 + quad * 4 + 16];
                        f16x8 vf;
#pragma unroll
                        for (int e = 0; e < 4; e++) { vf[e] = vlo[e]; vf[e + 4] = vhi[e]; }
#pragma unroll
                        for (int qt = 0; qt < 2; qt++)
                            o[dt][qt] = __builtin_amdgcn_mfma_f32_16x16x32_f16(vf, pw[s2][qt].v8, o[dt][qt], 0, 0, 0);
                    }
            }
        }

        // reduce l across quads (deferred), write partials
        float l_i[2];
#pragma unroll
        for (int qt = 0; qt < 2; qt++) {
            float v = l_lane[qt];
            v += __shfl_xor(v, 16);
            v += __shfl_xor(v, 32);
            l_i[qt] = v;
        }
#pragma unroll
        for (int dt = 0; dt < 4; dt++)
#pragma unroll
            for (int qt = 0; qt < 2; qt++) {
                int row = wrow0 + qt * 16 + lr;
                float* dst = Opart + ((size_t)sp * TSEQ + row) * EMBED + h * DHEAD + dt * 16 + quad * 4;
                *(f32x4*)dst = o[dt][qt];
            }
#pragma unroll
        for (int qt = 0; qt < 2; qt++)
            if (quad == 0) {
                int row = wrow0 + qt * 16 + lr;
                ml[((size_t)sp * TSEQ + row) * NHEAD + h] = make_float2(m_i[qt], l_i[qt]);
            }
    }
}

// ---------------- merge split-K partials -> ctx f16
__global__ __launch_bounds__(256) void attn_merge_kernel(const float* __restrict__ Opart,
                                                         const float2* __restrict__ ml,
                                                         f16* __restrict__ ctx) {
    const int row = blockIdx.x;
    const int t = threadIdx.x;
    __shared__ float wgt[NSPLIT][NHEAD];
    if (t < NHEAD) {
        float m[NSPLIT], l[NSPLIT];
        float M = -INFINITY;
#pragma unroll
        for (int s = 0; s < NSPLIT; s++) {
            float2 v = ml[((size_t)s * TSEQ + row) * NHEAD + t];
            m[s] = v.x; l[s] = v.y;
            M = fmaxf(M, m[s]);
        }
        float L = 0.f;
        float w[NSPLIT];
#pragma unroll
        for (int s = 0; s < NSPLIT; s++) {
            w[s] = exp2f(m[s] - M);
            L += l[s] * w[s];
        }
        float rL = 1.0f / L;
#pragma unroll
        for (int s = 0; s < NSPLIT; s++) wgt[s][t] = w[s] * rL;
    }
    __syncthreads();
#pragma unroll
    for (int p = 0; p < 3; p++) {
        int c = t + p * 256;
        int h = c >> 6;
        float acc = 0.f;
#pragma unroll
        for (int s = 0; s < NSPLIT; s++)
            acc += wgt[s][h] * Opart[((size_t)s * TSEQ + row) * EMBED + c];
        ctx[(size_t)row * EMBED + c] = (f16)acc;
    }
}

extern "C" void kernel_launch(void* const* d_in, const int* in_sizes, int n_in,
                              void* d_out, int out_size, void* d_ws, size_t ws_size,
                              hipStream_t stream) {
    const float* x     = (const float*)d_in[0];
    const float* Wq    = (const float*)d_in[1];
    const float* bq    = (const float*)d_in[2];
    const float* Wk    = (const float*)d_in[3];
    const float* bk    = (const float*)d_in[4];
    const float* Wv    = (const float*)d_in[5];
    const float* bv    = (const float*)d_in[6];
    const float* Wo    = (const float*)d_in[7];
    const float* bo    = (const float*)d_in[8];
    const float* ln1_g = (const float*)d_in[9];
    const float* ln1_b = (const float*)d_in[10];
    const float* ln2_g = (const float*)d_in[11];
    const float* ln2_b = (const float*)d_in[12];
    const float* W1    = (const float*)d_in[13];
    const float* b1    = (const float*)d_in[14];
    const float* W2    = (const float*)d_in[15];
    const float* b2    = (const float*)d_in[16];

    char* p = (char*)d_ws;
    auto alloc = [&](size_t bytes) -> void* {
        void* r = (void*)p;
        p += (bytes + 255) & ~(size_t)255;
        return r;
    };
    f16*   WqkvT = (f16*)alloc((size_t)CQKV * EMBED * 2);
    f16*   WoT   = (f16*)alloc((size_t)EMBED * EMBED * 2);
    f16*   W1T   = (f16*)alloc((size_t)FFN_D * EMBED * 2);
    f16*   W2T   = (f16*)alloc((size_t)EMBED * FFN_D * 2);
    float* bqkv  = (float*)alloc((size_t)CQKV * 4);
    float* hf    = (float*)alloc((size_t)TSEQ * EMBED * 4);
    f16*   hh    = (f16*)alloc((size_t)TSEQ * EMBED * 2);
    f16*   qkv   = (f16*)alloc((size_t)TSEQ * CQKV * 2);
    f16*   vT    = (f16*)alloc((size_t)EMBED * TSEQ * 2);
    f16*   ctx   = (f16*)alloc((size_t)TSEQ * EMBED * 2);
    float* x2    = (float*)alloc((size_t)TSEQ * EMBED * 4);
    float* h2f   = (float*)alloc((size_t)TSEQ * EMBED * 4);
    f16*   h2h   = (f16*)alloc((size_t)TSEQ * EMBED * 2);
    f16*   m1    = (f16*)alloc((size_t)TSEQ * FFN_D * 2);
    int*   ctr   = (int*)alloc(256);

    // split-K attention partials ALIAS the post-attention buffers (x2..m1 span
    // 56.7 MB >= 50.3+1.6 MB; attention+merge complete before x2 is written)
    float*  Opart = x2;                                        // [NSPLIT][TSEQ][768] f32
    float2* mlbuf = (float2*)(x2 + (size_t)NSPLIT * TSEQ * EMBED);

    dim3 blk(256);
    tconv_kernel<<<dim3(EMBED / 32, EMBED / 32), blk, 0, stream>>>(Wq, WqkvT, EMBED, EMBED);
    tconv_kernel<<<dim3(EMBED / 32, EMBED / 32), blk, 0, stream>>>(Wk, WqkvT + (size_t)EMBED * EMBED, EMBED, EMBED);
    tconv_kernel<<<dim3(EMBED / 32, EMBED / 32), blk, 0, stream>>>(Wv, WqkvT + (size_t)2 * EMBED * EMBED, EMBED, EMBED);
    tconv_kernel<<<dim3(EMBED / 32, EMBED / 32), blk, 0, stream>>>(Wo, WoT, EMBED, EMBED);
    tconv_kernel<<<dim3(FFN_D / 32, EMBED / 32), blk, 0, stream>>>(W1, W1T, EMBED, FFN_D);
    tconv_kernel<<<dim3(EMBED / 32, FFN_D / 32), blk, 0, stream>>>(W2, W2T, FFN_D, EMBED);
    concat3_kernel<<<dim3(9), blk, 0, stream>>>(bq, bk, bv, bqkv);

    // LN1
    ln_kernel<<<dim3(TSEQ), blk, 0, stream>>>(x, ln1_g, ln1_b, hf, hh);
    // QKV fused GEMM (q section pre-scaled by SC2Q in epilogue)
    gemm_kernel<0, 128><<<dim3(CQKV / 128, TSEQ / 128), blk, 0, stream>>>(
        hh, WqkvT, bqkv, nullptr, nullptr, qkv, TSEQ, CQKV, EMBED);
    // V transpose for attention A-operand
    vtrans_kernel<<<dim3(TSEQ / 32, EMBED / 32), blk, 0, stream>>>(qkv, vT);
    // persistent attention (atomic work queue) + merge
    (void)hipMemsetAsync(ctr, 0, sizeof(int), stream);
    attn_kernel<<<dim3(1280), blk, 0, stream>>>(qkv, vT, Opart, mlbuf, ctr);
    attn_merge_kernel<<<dim3(TSEQ), blk, 0, stream>>>(Opart, mlbuf, ctx);
    // Wo GEMM + residual(h)  (overwrites the Opart alias region - partials are dead)
    gemm_kernel<1, 64><<<dim3(EMBED / 64, TSEQ / 128), blk, 0, stream>>>(
        ctx, WoT, bo, hf, x2, nullptr, TSEQ, EMBED, EMBED);
    // LN2
    ln_kernel<<<dim3(TSEQ), blk, 0, stream>>>(x2, ln2_g, ln2_b, h2f, h2h);
    // FFN1 + gelu
    gemm_kernel<2, 128><<<dim3(FFN_D / 128, TSEQ / 128), blk, 0, stream>>>(
        h2h, W1T, b1, nullptr, nullptr, m1, TSEQ, FFN_D, EMBED);
    // FFN2 + residual(h2) -> fp32 out
    gemm_kernel<1, 64><<<dim3(EMBED / 64, TSEQ / 128), blk, 0, stream>>>(
        m1, W2T, b2, h2f, (float*)d_out, nullptr, TSEQ, EMBED, FFN_D);
}

// Round 8
// 389.425 us; speedup vs baseline: 1.2742x; 1.0294x over previous
//
#include <hip/hip_runtime.h>
#include <math.h>

#define EMBED 768
#define FFN_D 3072
#define TSEQ 4096
#define NHEAD 12
#define DHEAD 64
#define CQKV 2304   // 3*EMBED
#define NSPLIT 2
#define NQITEMS 96                     // items per XCD queue: 32 qb x 3 units
#define SC2Q 0.180336880111120419f     // 0.125 * log2(e), folded into Q in QKV epilogue

typedef _Float16 f16;
typedef __attribute__((ext_vector_type(2))) _Float16 f16x2;
typedef __attribute__((ext_vector_type(4))) _Float16 f16x4;
typedef __attribute__((ext_vector_type(8))) _Float16 f16x8;
typedef __attribute__((ext_vector_type(4))) float f32x4;

__device__ __forceinline__ f16x2 pkrtz(float a, float b) {
    return __builtin_bit_cast(f16x2, __builtin_amdgcn_cvt_pkrtz(a, b));
}

// async global->LDS, 16B per lane; lds base wave-uniform, lane i lands at base + i*16
__device__ __forceinline__ void gload16(const f16* g, f16* lds) {
    __builtin_amdgcn_global_load_lds((const __attribute__((address_space(1))) void*)g,
                                     (__attribute__((address_space(3))) void*)lds, 16, 0, 0);
}

// ---------------- fused weight prep: 6 transpose+convert passes + bias concat, ONE launch
// tiles: Wq 576 | Wk 576 | Wv 576 | Wo 576 | W1 2304 | W2 2304 | +1 bias block = 6913
__global__ __launch_bounds__(256) void prep_kernel(const float* __restrict__ Wq,
                                                   const float* __restrict__ Wk,
                                                   const float* __restrict__ Wv,
                                                   const float* __restrict__ Wo,
                                                   const float* __restrict__ W1,
                                                   const float* __restrict__ W2,
                                                   const float* __restrict__ bq,
                                                   const float* __restrict__ bk,
                                                   const float* __restrict__ bv,
                                                   f16* __restrict__ WqkvT,
                                                   f16* __restrict__ WoT,
                                                   f16* __restrict__ W1T,
                                                   f16* __restrict__ W2T,
                                                   float* __restrict__ bqkv) {
    const int b = blockIdx.x;
    const int t = threadIdx.x;
    if (b == 6912) {   // bias concat
#pragma unroll
        for (int i = 0; i < 9; i++) {
            int idx = i * 256 + t;
            if (idx < 768) bqkv[idx] = bq[idx];
            else if (idx < 1536) bqkv[idx] = bk[idx - 768];
            else if (idx < 2304) bqkv[idx] = bv[idx - 1536];
        }
        return;
    }
    const float* W; f16* WT; int din, dout, local;
    if (b < 576)       { W = Wq; WT = WqkvT;                         din = 768;  dout = 768;  local = b; }
    else if (b < 1152) { W = Wk; WT = WqkvT + 768 * 768;             din = 768;  dout = 768;  local = b - 576; }
    else if (b < 1728) { W = Wv; WT = WqkvT + 2 * 768 * 768;         din = 768;  dout = 768;  local = b - 1152; }
    else if (b < 2304) { W = Wo; WT = WoT;                           din = 768;  dout = 768;  local = b - 1728; }
    else if (b < 4608) { W = W1; WT = W1T;                           din = 768;  dout = 3072; local = b - 2304; }
    else               { W = W2; WT = W2T;                           din = 3072; dout = 768;  local = b - 4608; }
    const int tx2 = dout / 32;
    const int j0 = (local % tx2) * 32;
    const int i0 = (local / tx2) * 32;
    __shared__ float tile[32][33];
    const int tx = t & 31;
    const int ty = t >> 5;
#pragma unroll
    for (int rr = ty; rr < 32; rr += 8)
        tile[rr][tx] = W[(size_t)(i0 + rr) * dout + j0 + tx];
    __syncthreads();
#pragma unroll
    for (int rr = ty; rr < 32; rr += 8)
        WT[(size_t)(j0 + rr) * din + i0 + tx] = (f16)tile[tx][rr];
}

// ---------------- f16 transpose of the V section of qkv -> vT[h*64+d][t]
__global__ __launch_bounds__(256) void vtrans_kernel(const f16* __restrict__ qkv,
                                                     f16* __restrict__ vT) {
    __shared__ f16 tile[32][34];
    const int t0 = blockIdx.x * 32;
    const int c0 = blockIdx.y * 32;
    const int tx = threadIdx.x & 31;
    const int ty = threadIdx.x >> 5;
#pragma unroll
    for (int rr = ty; rr < 32; rr += 8)
        tile[rr][tx] = qkv[(size_t)(t0 + rr) * CQKV + 2 * EMBED + c0 + tx];
    __syncthreads();
#pragma unroll
    for (int rr = ty; rr < 32; rr += 8)
        vT[(size_t)(c0 + rr) * TSEQ + t0 + tx] = tile[tx][rr];
}

// ---------------- LayerNorm row kernel (768 wide), writes f32 + f16
__global__ __launch_bounds__(256) void ln_kernel(const float* __restrict__ x,
                                                 const float* __restrict__ g,
                                                 const float* __restrict__ b,
                                                 float* __restrict__ hf,
                                                 f16* __restrict__ hh) {
    const int row = blockIdx.x;
    const float* xr = x + (size_t)row * EMBED;
    const int t = threadIdx.x;
    float v0 = xr[t], v1 = xr[t + 256], v2 = xr[t + 512];
    float s = v0 + v1 + v2;
#pragma unroll
    for (int m = 1; m < 64; m <<= 1) s += __shfl_xor(s, m);
    __shared__ float red[4], red2[4];
    const int wid = t >> 6, lane = t & 63;
    if (lane == 0) red[wid] = s;
    __syncthreads();
    float mean = (red[0] + red[1] + red[2] + red[3]) * (1.0f / 768.0f);
    float d0 = v0 - mean, d1 = v1 - mean, d2 = v2 - mean;
    float ss = d0 * d0 + d1 * d1 + d2 * d2;
#pragma unroll
    for (int m = 1; m < 64; m <<= 1) ss += __shfl_xor(ss, m);
    if (lane == 0) red2[wid] = ss;
    __syncthreads();
    float inv = rsqrtf((red2[0] + red2[1] + red2[2] + red2[3]) * (1.0f / 768.0f) + 1e-5f);
    float o0 = d0 * inv * g[t] + b[t];
    float o1 = d1 * inv * g[t + 256] + b[t + 256];
    float o2 = d2 * inv * g[t + 512] + b[t + 512];
    size_t base = (size_t)row * EMBED;
    hf[base + t] = o0; hf[base + t + 256] = o1; hf[base + t + 512] = o2;
    hh[base + t] = (f16)o0; hh[base + t + 256] = (f16)o1; hh[base + t + 512] = (f16)o2;
}

// ---------------- GEMM: C[M][N] = A[M][K] * BT[N][K]^T + bias
// BK=64, XOR-swizzled LDS, global_load_lds staging, swapped MFMA operands
// EPI 0: out fp16 (QKV: cols<768 scaled by SC2Q)  EPI 1: fp32 acc+bias+res  EPI 2: fp16 gelu
template <int EPI, int BN>
__global__ __launch_bounds__(256) void gemm_kernel(const f16* __restrict__ A,
                                                   const f16* __restrict__ BT,
                                                   const float* __restrict__ bias,
                                                   const float* __restrict__ res,
                                                   float* __restrict__ outf,
                                                   f16* __restrict__ outh,
                                                   int M, int N, int K) {
    constexpr int JN = BN / 32;
    constexpr int BROWS = BN / 4;
    __shared__ __align__(16) f16 As[128][64];
    __shared__ __align__(16) f16 Bs[BN][64];
    const int t = threadIdx.x;
    const int m0 = blockIdx.y * 128;
    const int n0 = blockIdx.x * BN;
    const int wid = t >> 6;
    const int lane = t & 63;
    const int wm = (wid >> 1) * 64;
    const int wn = (wid & 1) * (BN / 2);
    const int lr = lane & 15;
    const int quad = lane >> 4;
    const int sr = lane >> 3;            // 0..7 (row within an 8-row DMA call)
    const int scn = (lane & 7) ^ sr;     // swizzled source chunk (8 f16 per chunk)
    const int xv = lr & 7;               // read-side xor

    f32x4 zero = {0.f, 0.f, 0.f, 0.f};
    f32x4 acc[4][JN];
#pragma unroll
    for (int i = 0; i < 4; i++)
#pragma unroll
        for (int j = 0; j < JN; j++) acc[i][j] = zero;

    const f16* Ap = A + (size_t)(m0 + wid * 32 + sr) * K + scn * 8;
    const f16* Bp = BT + (size_t)(n0 + wid * BROWS + sr) * K + scn * 8;

    for (int k0 = 0; k0 < K; k0 += 64) {
        __syncthreads();
#pragma unroll
        for (int c = 0; c < 4; c++)
            gload16(Ap + (size_t)(c * 8) * K + k0, &As[wid * 32 + c * 8][0]);
#pragma unroll
        for (int c = 0; c < BROWS / 8; c++)
            gload16(Bp + (size_t)(c * 8) * K + k0, &Bs[wid * BROWS + c * 8][0]);
        __syncthreads();
#pragma unroll
        for (int ks = 0; ks < 2; ks++) {
            f16x8 af[4], bf[JN];
#pragma unroll
            for (int i = 0; i < 4; i++)
                af[i] = *(const f16x8*)&As[wm + i * 16 + lr][((ks * 4 + quad) ^ xv) * 8];
#pragma unroll
            for (int j = 0; j < JN; j++)
                bf[j] = *(const f16x8*)&Bs[wn + j * 16 + lr][((ks * 4 + quad) ^ xv) * 8];
#pragma unroll
            for (int i = 0; i < 4; i++)
#pragma unroll
                for (int j = 0; j < JN; j++)
                    acc[i][j] = __builtin_amdgcn_mfma_f32_16x16x32_f16(bf[j], af[i], acc[i][j], 0, 0, 0);
        }
    }

    // acc[i][j][r] = C[row = m0+wm+i*16+lr][col = n0+wn+j*16+quad*4+r]
#pragma unroll
    for (int i = 0; i < 4; i++) {
        const int row = m0 + wm + i * 16 + lr;
#pragma unroll
        for (int j = 0; j < JN; j++) {
            const int col = n0 + wn + j * 16 + quad * 4;
            const float4 bv = *(const float4*)&bias[col];
            float v0 = acc[i][j][0] + bv.x;
            float v1 = acc[i][j][1] + bv.y;
            float v2 = acc[i][j][2] + bv.z;
            float v3 = acc[i][j][3] + bv.w;
            const size_t idx = (size_t)row * N + col;
            if (EPI == 0) {
                const float qs = (col < EMBED) ? SC2Q : 1.0f;
                f16x4 hv = {(f16)(v0 * qs), (f16)(v1 * qs), (f16)(v2 * qs), (f16)(v3 * qs)};
                *(f16x4*)&outh[idx] = hv;
            } else if (EPI == 1) {
                const float4 rr = *(const float4*)&res[idx];
                f32x4 ov = {v0 + rr.x, v1 + rr.y, v2 + rr.z, v3 + rr.w};
                *(f32x4*)&outf[idx] = ov;
            } else {
                f16x4 hv = {(f16)(0.5f * v0 * (1.0f + erff(v0 * 0.70710678118654752f))),
                            (f16)(0.5f * v1 * (1.0f + erff(v1 * 0.70710678118654752f))),
                            (f16)(0.5f * v2 * (1.0f + erff(v2 * 0.70710678118654752f))),
                            (f16)(0.5f * v3 * (1.0f + erff(v3 * 0.70710678118654752f)))};
                *(f16x4*)&outh[idx] = hv;
            }
        }
    }
}

// ---------------- persistent flash attention, XCD-sliced work queues
// Queue q = blockIdx.x & 7 (round-robin block->XCD heuristic; correctness independent).
// Queue q owns (h,sp) units {q, q+8, q+16} (NSPLIT=2 -> 24 units, 3 per queue, 528
// tiles each -> perfectly balanced). Items ordered qb-descending. Each XCD's K/V
// working set ~4-5 MB -> fits its private L2.
__global__ __launch_bounds__(256) void attn_kernel(const f16* __restrict__ qkv,
                                                   const f16* __restrict__ vT,
                                                   float* __restrict__ Opart,
                                                   float2* __restrict__ ml,
                                                   int* __restrict__ ctr) {
    __shared__ __align__(16) f16 Ks[64][72];   // [key][d]
    __shared__ __align__(16) f16 Vt[64][72];   // [d][key]
    __shared__ int s_item;
    const int t = threadIdx.x;
    const int wid = t >> 6;
    const int lane = t & 63;
    const int lr = lane & 15;
    const int quad = lane >> 4;
    const int srow = t >> 3;        // 0..31 (staging)
    const int scol = (t & 7) * 8;   // 0..56
    const int xq = blockIdx.x & 7;

    for (;;) {
        __syncthreads();
        if (t == 0) s_item = atomicAdd(&ctr[xq], 1);
        __syncthreads();
        const int item = s_item;
        if (item >= NQITEMS) return;
        const int qb = 31 - item / 3;
        const int u = xq + 8 * (item % 3);   // unit 0..23
        const int h = u >> 1;
        const int sp = u & 1;
        const int q0 = qb * 128;

        const int chunk = qb + 1;            // nkb = 2qb+2, split exactly in half
        const int kb0 = sp * chunk;
        const int kb1 = kb0 + chunk;
        const int wrow0 = q0 + wid * 32;

        float m_i[2] = {-INFINITY, -INFINITY};
        float l_lane[2] = {0.f, 0.f};
        f32x4 zero = {0.f, 0.f, 0.f, 0.f};
        f32x4 o[4][2];
#pragma unroll
        for (int dt = 0; dt < 4; dt++)
#pragma unroll
            for (int qt = 0; qt < 2; qt++) o[dt][qt] = zero;

        f16x8 qf[2][2];
        int4 kreg[2], vreg[2];
        const f16* kbase = qkv + EMBED + (size_t)h * DHEAD;
        const f16* vbase = vT + (size_t)h * DHEAD * TSEQ;
        {
#pragma unroll
            for (int qt = 0; qt < 2; qt++)
#pragma unroll
                for (int dh = 0; dh < 2; dh++)
                    qf[qt][dh] = *(const f16x8*)(qkv + (size_t)(wrow0 + qt * 16 + lr) * CQKV
                                                 + h * DHEAD + dh * 32 + quad * 8);
            const int k0 = kb0 * 64;
#pragma unroll
            for (int p = 0; p < 2; p++) {
                kreg[p] = *(const int4*)(kbase + (size_t)(k0 + p * 32 + srow) * CQKV + scol);
                vreg[p] = *(const int4*)(vbase + (size_t)(p * 32 + srow) * TSEQ + k0 + scol);
            }
        }

        for (int kb = kb0; kb < kb1; ++kb) {
            const int k0 = kb * 64;
            __syncthreads();
#pragma unroll
            for (int p = 0; p < 2; p++) {
                *(int4*)&Ks[p * 32 + srow][scol] = kreg[p];
                *(int4*)&Vt[p * 32 + srow][scol] = vreg[p];
            }
            __syncthreads();
            if (kb + 1 < kb1) {
                const int kn = (kb + 1) * 64;
#pragma unroll
                for (int p = 0; p < 2; p++) {
                    kreg[p] = *(const int4*)(kbase + (size_t)(kn + p * 32 + srow) * CQKV + scol);
                    vreg[p] = *(const int4*)(vbase + (size_t)(p * 32 + srow) * TSEQ + kn + scol);
                }
            }

            if (k0 <= wrow0 + 31) {   // wave-uniform compute guard (barriers always hit)
                f32x4 s[4][2];
#pragma unroll
                for (int kt = 0; kt < 4; kt++)
#pragma unroll
                    for (int qt = 0; qt < 2; qt++) s[kt][qt] = zero;
#pragma unroll
                for (int dh = 0; dh < 2; dh++) {
#pragma unroll
                    for (int kt = 0; kt < 4; kt++) {
                        f16x8 kf = *(const f16x8*)&Ks[kt * 16 + lr][dh * 32 + quad * 8];
#pragma unroll
                        for (int qt = 0; qt < 2; qt++)
                            s[kt][qt] = __builtin_amdgcn_mfma_f32_16x16x32_f16(kf, qf[qt][dh], s[kt][qt], 0, 0, 0);
                    }
                }
                if (k0 + 63 > wrow0) {
#pragma unroll
                    for (int kt = 0; kt < 4; kt++)
#pragma unroll
                        for (int qt = 0; qt < 2; qt++)
#pragma unroll
                            for (int r = 0; r < 4; r++) {
                                int key = k0 + kt * 16 + quad * 4 + r;
                                int row = wrow0 + qt * 16 + lr;
                                if (key > row) s[kt][qt][r] = -INFINITY;
                            }
                }
                float al[2];
#pragma unroll
                for (int qt = 0; qt < 2; qt++) {
                    float mx = -INFINITY;
#pragma unroll
                    for (int kt = 0; kt < 4; kt++)
#pragma unroll
                        for (int r = 0; r < 4; r++) mx = fmaxf(mx, s[kt][qt][r]);
                    mx = fmaxf(mx, __shfl_xor(mx, 16));
                    mx = fmaxf(mx, __shfl_xor(mx, 32));
                    float mn = fmaxf(m_i[qt], mx);
                    al[qt] = exp2f(m_i[qt] - mn);
                    m_i[qt] = mn;
                }
                union PW { f16x8 v8; f16x2 h2[4]; };
                PW pw[2][2];
                float rs[2] = {0.f, 0.f};
#pragma unroll
                for (int kt = 0; kt < 4; kt++)
#pragma unroll
                    for (int qt = 0; qt < 2; qt++) {
                        float p0 = exp2f(s[kt][qt][0] - m_i[qt]);
                        float p1 = exp2f(s[kt][qt][1] - m_i[qt]);
                        float p2 = exp2f(s[kt][qt][2] - m_i[qt]);
                        float p3 = exp2f(s[kt][qt][3] - m_i[qt]);
                        rs[qt] += (p0 + p1) + (p2 + p3);
                        pw[kt >> 1][qt].h2[(kt & 1) * 2]     = pkrtz(p0, p1);
                        pw[kt >> 1][qt].h2[(kt & 1) * 2 + 1] = pkrtz(p2, p3);
                    }
#pragma unroll
                for (int qt = 0; qt < 2; qt++) l_lane[qt] = l_lane[qt] * al[qt] + rs[qt];
#pragma unroll
                for (int dt = 0; dt < 4; dt++)
#pragma unroll
                    for (int qt = 0; qt < 2; qt++)
#pragma unroll
                        for (int r = 0; r < 4; r++) o[dt][qt][r] *= al[qt];
#pragma unroll
                for (int s2 = 0; s2 < 2; s2++)
#pragma unroll
                    for (int dt = 0; dt < 4; dt++) {
                        f16x4 vlo = *(const f16x4*)&Vt[dt * 16 + lr][s2 * 32 + quad * 4];
                        f16x4 vhi = *(const f16x4*)&Vt[dt * 16 + lr][s2 * 32 + quad * 4 + 16];
                        f16x8 vf;
#pragma unroll
                        for (int e = 0; e < 4; e++) { vf[e] = vlo[e]; vf[e + 4] = vhi[e]; }
#pragma unroll
                        for (int qt = 0; qt < 2; qt++)
                            o[dt][qt] = __builtin_amdgcn_mfma_f32_16x16x32_f16(vf, pw[s2][qt].v8, o[dt][qt], 0, 0, 0);
                    }
            }
        }

        float l_i[2];
#pragma unroll
        for (int qt = 0; qt < 2; qt++) {
            float v = l_lane[qt];
            v += __shfl_xor(v, 16);
            v += __shfl_xor(v, 32);
            l_i[qt] = v;
        }
#pragma unroll
        for (int dt = 0; dt < 4; dt++)
#pragma unroll
            for (int qt = 0; qt < 2; qt++) {
                int row = wrow0 + qt * 16 + lr;
                float* dst = Opart + ((size_t)sp * TSEQ + row) * EMBED + h * DHEAD + dt * 16 + quad * 4;
                *(f32x4*)dst = o[dt][qt];
            }
#pragma unroll
        for (int qt = 0; qt < 2; qt++)
            if (quad == 0) {
                int row = wrow0 + qt * 16 + lr;
                ml[((size_t)sp * TSEQ + row) * NHEAD + h] = make_float2(m_i[qt], l_i[qt]);
            }
    }
}

// ---------------- merge split-K partials -> ctx f16
__global__ __launch_bounds__(256) void attn_merge_kernel(const float* __restrict__ Opart,
                                                         const float2* __restrict__ ml,
                                                         f16* __restrict__ ctx) {
    const int row = blockIdx.x;
    const int t = threadIdx.x;
    __shared__ float wgt[NSPLIT][NHEAD];
    if (t < NHEAD) {
        float m[NSPLIT], l[NSPLIT];
        float M = -INFINITY;
#pragma unroll
        for (int s = 0; s < NSPLIT; s++) {
            float2 v = ml[((size_t)s * TSEQ + row) * NHEAD + t];
            m[s] = v.x; l[s] = v.y;
            M = fmaxf(M, m[s]);
        }
        float L = 0.f;
        float w[NSPLIT];
#pragma unroll
        for (int s = 0; s < NSPLIT; s++) {
            w[s] = exp2f(m[s] - M);
            L += l[s] * w[s];
        }
        float rL = 1.0f / L;
#pragma unroll
        for (int s = 0; s < NSPLIT; s++) wgt[s][t] = w[s] * rL;
    }
    __syncthreads();
#pragma unroll
    for (int p = 0; p < 3; p++) {
        int c = t + p * 256;
        int h = c >> 6;
        float acc = 0.f;
#pragma unroll
        for (int s = 0; s < NSPLIT; s++)
            acc += wgt[s][h] * Opart[((size_t)s * TSEQ + row) * EMBED + c];
        ctx[(size_t)row * EMBED + c] = (f16)acc;
    }
}

extern "C" void kernel_launch(void* const* d_in, const int* in_sizes, int n_in,
                              void* d_out, int out_size, void* d_ws, size_t ws_size,
                              hipStream_t stream) {
    const float* x     = (const float*)d_in[0];
    const float* Wq    = (const float*)d_in[1];
    const float* bq    = (const float*)d_in[2];
    const float* Wk    = (const float*)d_in[3];
    const float* bk    = (const float*)d_in[4];
    const float* Wv    = (const float*)d_in[5];
    const float* bv    = (const float*)d_in[6];
    const float* Wo    = (const float*)d_in[7];
    const float* bo    = (const float*)d_in[8];
    const float* ln1_g = (const float*)d_in[9];
    const float* ln1_b = (const float*)d_in[10];
    const float* ln2_g = (const float*)d_in[11];
    const float* ln2_b = (const float*)d_in[12];
    const float* W1    = (const float*)d_in[13];
    const float* b1    = (const float*)d_in[14];
    const float* W2    = (const float*)d_in[15];
    const float* b2    = (const float*)d_in[16];

    char* p = (char*)d_ws;
    auto alloc = [&](size_t bytes) -> void* {
        void* r = (void*)p;
        p += (bytes + 255) & ~(size_t)255;
        return r;
    };
    f16*   WqkvT = (f16*)alloc((size_t)CQKV * EMBED * 2);
    f16*   WoT   = (f16*)alloc((size_t)EMBED * EMBED * 2);
    f16*   W1T   = (f16*)alloc((size_t)FFN_D * EMBED * 2);
    f16*   W2T   = (f16*)alloc((size_t)EMBED * FFN_D * 2);
    float* bqkv  = (float*)alloc((size_t)CQKV * 4);
    float* hf    = (float*)alloc((size_t)TSEQ * EMBED * 4);
    f16*   hh    = (f16*)alloc((size_t)TSEQ * EMBED * 2);
    f16*   qkv   = (f16*)alloc((size_t)TSEQ * CQKV * 2);
    f16*   vT    = (f16*)alloc((size_t)EMBED * TSEQ * 2);
    f16*   ctx   = (f16*)alloc((size_t)TSEQ * EMBED * 2);
    float* x2    = (float*)alloc((size_t)TSEQ * EMBED * 4);
    float* h2f   = (float*)alloc((size_t)TSEQ * EMBED * 4);
    f16*   h2h   = (f16*)alloc((size_t)TSEQ * EMBED * 2);
    f16*   m1    = (f16*)alloc((size_t)TSEQ * FFN_D * 2);
    int*   ctr   = (int*)alloc(256);

    // split-K attention partials ALIAS the post-attention buffers (x2..m1 span
    // 56.7 MB >= 25.2+0.8 MB; attention+merge complete before x2 is written)
    float*  Opart = x2;                                        // [NSPLIT][TSEQ][768] f32
    float2* mlbuf = (float2*)(x2 + (size_t)NSPLIT * TSEQ * EMBED);

    dim3 blk(256);
    // fused weight prep (6 transposes + bias concat, one launch)
    prep_kernel<<<dim3(6913), blk, 0, stream>>>(Wq, Wk, Wv, Wo, W1, W2, bq, bk, bv,
                                                WqkvT, WoT, W1T, W2T, bqkv);
    // LN1
    ln_kernel<<<dim3(TSEQ), blk, 0, stream>>>(x, ln1_g, ln1_b, hf, hh);
    // QKV fused GEMM (q section pre-scaled by SC2Q in epilogue)
    gemm_kernel<0, 128><<<dim3(CQKV / 128, TSEQ / 128), blk, 0, stream>>>(
        hh, WqkvT, bqkv, nullptr, nullptr, qkv, TSEQ, CQKV, EMBED);
    // V transpose for attention A-operand
    vtrans_kernel<<<dim3(TSEQ / 32, EMBED / 32), blk, 0, stream>>>(qkv, vT);
    // persistent attention (8 XCD-sliced queues) + merge
    (void)hipMemsetAsync(ctr, 0, 256, stream);
    attn_kernel<<<dim3(1280), blk, 0, stream>>>(qkv, vT, Opart, mlbuf, ctr);
    attn_merge_kernel<<<dim3(TSEQ), blk, 0, stream>>>(Opart, mlbuf, ctx);
    // Wo GEMM + residual(h)  (overwrites the Opart alias region - partials are dead)
    gemm_kernel<1, 64><<<dim3(EMBED / 64, TSEQ / 128), blk, 0, stream>>>(
        ctx, WoT, bo, hf, x2, nullptr, TSEQ, EMBED, EMBED);
    // LN2
    ln_kernel<<<dim3(TSEQ), blk, 0, stream>>>(x2, ln2_g, ln2_b, h2f, h2h);
    // FFN1 + gelu
    gemm_kernel<2, 128><<<dim3(FFN_D / 128, TSEQ / 128), blk, 0, stream>>>(
        h2h, W1T, b1, nullptr, nullptr, m1, TSEQ, FFN_D, EMBED);
    // FFN2 + residual(h2) -> fp32 out
    gemm_kernel<1, 64><<<dim3(EMBED / 64, TSEQ / 128), blk, 0, stream>>>(
        m1, W2T, b2, h2f, (float*)d_out, nullptr, TSEQ, EMBED, FFN_D);
}

// Round 9
// 386.662 us; speedup vs baseline: 1.2833x; 1.0071x over previous
//
#include <hip/hip_runtime.h>
#include <math.h>

#define EMBED 768
#define FFN_D 3072
#define TSEQ 4096
#define NHEAD 12
#define DHEAD 64
#define CQKV 2304   // 3*EMBED
#define NSPLIT 4
#define NQITEMS 192                    // per XCD queue: 32 qb x 6 units
#define SC2Q 0.180336880111120419f     // 0.125 * log2(e), folded into Q in QKV epilogue

typedef _Float16 f16;
typedef __attribute__((ext_vector_type(2))) _Float16 f16x2;
typedef __attribute__((ext_vector_type(4))) _Float16 f16x4;
typedef __attribute__((ext_vector_type(8))) _Float16 f16x8;
typedef __attribute__((ext_vector_type(4))) float f32x4;

__device__ __forceinline__ f16x2 pkrtz(float a, float b) {
    return __builtin_bit_cast(f16x2, __builtin_amdgcn_cvt_pkrtz(a, b));
}

// async global->LDS, 16B per lane; lds base wave-uniform, lane i lands at base + i*16
__device__ __forceinline__ void gload16(const f16* g, f16* lds) {
    __builtin_amdgcn_global_load_lds((const __attribute__((address_space(1))) void*)g,
                                     (__attribute__((address_space(3))) void*)lds, 16, 0, 0);
}

// ---------------- fused weight prep: 6 transpose+convert passes + bias concat, ONE launch
__global__ __launch_bounds__(256) void prep_kernel(const float* __restrict__ Wq,
                                                   const float* __restrict__ Wk,
                                                   const float* __restrict__ Wv,
                                                   const float* __restrict__ Wo,
                                                   const float* __restrict__ W1,
                                                   const float* __restrict__ W2,
                                                   const float* __restrict__ bq,
                                                   const float* __restrict__ bk,
                                                   const float* __restrict__ bv,
                                                   f16* __restrict__ WqkvT,
                                                   f16* __restrict__ WoT,
                                                   f16* __restrict__ W1T,
                                                   f16* __restrict__ W2T,
                                                   float* __restrict__ bqkv) {
    const int b = blockIdx.x;
    const int t = threadIdx.x;
    if (b == 6912) {   // bias concat
#pragma unroll
        for (int i = 0; i < 9; i++) {
            int idx = i * 256 + t;
            if (idx < 768) bqkv[idx] = bq[idx];
            else if (idx < 1536) bqkv[idx] = bk[idx - 768];
            else if (idx < 2304) bqkv[idx] = bv[idx - 1536];
        }
        return;
    }
    const float* W; f16* WT; int din, dout, local;
    if (b < 576)       { W = Wq; WT = WqkvT;                         din = 768;  dout = 768;  local = b; }
    else if (b < 1152) { W = Wk; WT = WqkvT + 768 * 768;             din = 768;  dout = 768;  local = b - 576; }
    else if (b < 1728) { W = Wv; WT = WqkvT + 2 * 768 * 768;         din = 768;  dout = 768;  local = b - 1152; }
    else if (b < 2304) { W = Wo; WT = WoT;                           din = 768;  dout = 768;  local = b - 1728; }
    else if (b < 4608) { W = W1; WT = W1T;                           din = 768;  dout = 3072; local = b - 2304; }
    else               { W = W2; WT = W2T;                           din = 3072; dout = 768;  local = b - 4608; }
    const int tx2 = dout / 32;
    const int j0 = (local % tx2) * 32;
    const int i0 = (local / tx2) * 32;
    __shared__ float tile[32][33];
    const int tx = t & 31;
    const int ty = t >> 5;
#pragma unroll
    for (int rr = ty; rr < 32; rr += 8)
        tile[rr][tx] = W[(size_t)(i0 + rr) * dout + j0 + tx];
    __syncthreads();
#pragma unroll
    for (int rr = ty; rr < 32; rr += 8)
        WT[(size_t)(j0 + rr) * din + i0 + tx] = (f16)tile[tx][rr];
}

// ---------------- f16 transpose of the V section of qkv -> vT[h*64+d][t]
__global__ __launch_bounds__(256) void vtrans_kernel(const f16* __restrict__ qkv,
                                                     f16* __restrict__ vT) {
    __shared__ f16 tile[32][34];
    const int t0 = blockIdx.x * 32;
    const int c0 = blockIdx.y * 32;
    const int tx = threadIdx.x & 31;
    const int ty = threadIdx.x >> 5;
#pragma unroll
    for (int rr = ty; rr < 32; rr += 8)
        tile[rr][tx] = qkv[(size_t)(t0 + rr) * CQKV + 2 * EMBED + c0 + tx];
    __syncthreads();
#pragma unroll
    for (int rr = ty; rr < 32; rr += 8)
        vT[(size_t)(c0 + rr) * TSEQ + t0 + tx] = tile[tx][rr];
}

// ---------------- LayerNorm row kernel (768 wide), writes f32 + f16
__global__ __launch_bounds__(256) void ln_kernel(const float* __restrict__ x,
                                                 const float* __restrict__ g,
                                                 const float* __restrict__ b,
                                                 float* __restrict__ hf,
                                                 f16* __restrict__ hh) {
    const int row = blockIdx.x;
    const float* xr = x + (size_t)row * EMBED;
    const int t = threadIdx.x;
    float v0 = xr[t], v1 = xr[t + 256], v2 = xr[t + 512];
    float s = v0 + v1 + v2;
#pragma unroll
    for (int m = 1; m < 64; m <<= 1) s += __shfl_xor(s, m);
    __shared__ float red[4], red2[4];
    const int wid = t >> 6, lane = t & 63;
    if (lane == 0) red[wid] = s;
    __syncthreads();
    float mean = (red[0] + red[1] + red[2] + red[3]) * (1.0f / 768.0f);
    float d0 = v0 - mean, d1 = v1 - mean, d2 = v2 - mean;
    float ss = d0 * d0 + d1 * d1 + d2 * d2;
#pragma unroll
    for (int m = 1; m < 64; m <<= 1) ss += __shfl_xor(ss, m);
    if (lane == 0) red2[wid] = ss;
    __syncthreads();
    float inv = rsqrtf((red2[0] + red2[1] + red2[2] + red2[3]) * (1.0f / 768.0f) + 1e-5f);
    float o0 = d0 * inv * g[t] + b[t];
    float o1 = d1 * inv * g[t + 256] + b[t + 256];
    float o2 = d2 * inv * g[t + 512] + b[t + 512];
    size_t base = (size_t)row * EMBED;
    hf[base + t] = o0; hf[base + t + 256] = o1; hf[base + t + 512] = o2;
    hh[base + t] = (f16)o0; hh[base + t + 256] = (f16)o1; hh[base + t + 512] = (f16)o2;
}

// ---------------- GEMM: C[M][N] = A[M][K] * BT[N][K]^T + bias
// BK=64, XOR-swizzled LDS, global_load_lds staging, swapped MFMA operands
// EPI 0: out fp16 (QKV: cols<768 scaled by SC2Q)  EPI 1: fp32 acc+bias+res  EPI 2: fp16 gelu
template <int EPI, int BN>
__global__ __launch_bounds__(256) void gemm_kernel(const f16* __restrict__ A,
                                                   const f16* __restrict__ BT,
                                                   const float* __restrict__ bias,
                                                   const float* __restrict__ res,
                                                   float* __restrict__ outf,
                                                   f16* __restrict__ outh,
                                                   int M, int N, int K) {
    constexpr int JN = BN / 32;
    constexpr int BROWS = BN / 4;
    __shared__ __align__(16) f16 As[128][64];
    __shared__ __align__(16) f16 Bs[BN][64];
    const int t = threadIdx.x;
    const int m0 = blockIdx.y * 128;
    const int n0 = blockIdx.x * BN;
    const int wid = t >> 6;
    const int lane = t & 63;
    const int wm = (wid >> 1) * 64;
    const int wn = (wid & 1) * (BN / 2);
    const int lr = lane & 15;
    const int quad = lane >> 4;
    const int sr = lane >> 3;            // 0..7 (row within an 8-row DMA call)
    const int scn = (lane & 7) ^ sr;     // swizzled source chunk (8 f16 per chunk)
    const int xv = lr & 7;               // read-side xor

    f32x4 zero = {0.f, 0.f, 0.f, 0.f};
    f32x4 acc[4][JN];
#pragma unroll
    for (int i = 0; i < 4; i++)
#pragma unroll
        for (int j = 0; j < JN; j++) acc[i][j] = zero;

    const f16* Ap = A + (size_t)(m0 + wid * 32 + sr) * K + scn * 8;
    const f16* Bp = BT + (size_t)(n0 + wid * BROWS + sr) * K + scn * 8;

    for (int k0 = 0; k0 < K; k0 += 64) {
        __syncthreads();
#pragma unroll
        for (int c = 0; c < 4; c++)
            gload16(Ap + (size_t)(c * 8) * K + k0, &As[wid * 32 + c * 8][0]);
#pragma unroll
        for (int c = 0; c < BROWS / 8; c++)
            gload16(Bp + (size_t)(c * 8) * K + k0, &Bs[wid * BROWS + c * 8][0]);
        __syncthreads();
#pragma unroll
        for (int ks = 0; ks < 2; ks++) {
            f16x8 af[4], bf[JN];
#pragma unroll
            for (int i = 0; i < 4; i++)
                af[i] = *(const f16x8*)&As[wm + i * 16 + lr][((ks * 4 + quad) ^ xv) * 8];
#pragma unroll
            for (int j = 0; j < JN; j++)
                bf[j] = *(const f16x8*)&Bs[wn + j * 16 + lr][((ks * 4 + quad) ^ xv) * 8];
#pragma unroll
            for (int i = 0; i < 4; i++)
#pragma unroll
                for (int j = 0; j < JN; j++)
                    acc[i][j] = __builtin_amdgcn_mfma_f32_16x16x32_f16(bf[j], af[i], acc[i][j], 0, 0, 0);
        }
    }

    // acc[i][j][r] = C[row = m0+wm+i*16+lr][col = n0+wn+j*16+quad*4+r]
#pragma unroll
    for (int i = 0; i < 4; i++) {
        const int row = m0 + wm + i * 16 + lr;
#pragma unroll
        for (int j = 0; j < JN; j++) {
            const int col = n0 + wn + j * 16 + quad * 4;
            const float4 bv = *(const float4*)&bias[col];
            float v0 = acc[i][j][0] + bv.x;
            float v1 = acc[i][j][1] + bv.y;
            float v2 = acc[i][j][2] + bv.z;
            float v3 = acc[i][j][3] + bv.w;
            const size_t idx = (size_t)row * N + col;
            if (EPI == 0) {
                const float qs = (col < EMBED) ? SC2Q : 1.0f;
                f16x4 hv = {(f16)(v0 * qs), (f16)(v1 * qs), (f16)(v2 * qs), (f16)(v3 * qs)};
                *(f16x4*)&outh[idx] = hv;
            } else if (EPI == 1) {
                const float4 rr = *(const float4*)&res[idx];
                f32x4 ov = {v0 + rr.x, v1 + rr.y, v2 + rr.z, v3 + rr.w};
                *(f32x4*)&outf[idx] = ov;
            } else {
                f16x4 hv = {(f16)(0.5f * v0 * (1.0f + erff(v0 * 0.70710678118654752f))),
                            (f16)(0.5f * v1 * (1.0f + erff(v1 * 0.70710678118654752f))),
                            (f16)(0.5f * v2 * (1.0f + erff(v2 * 0.70710678118654752f))),
                            (f16)(0.5f * v3 * (1.0f + erff(v3 * 0.70710678118654752f)))};
                *(f16x4*)&outh[idx] = hv;
            }
        }
    }
}

// ---------------- persistent flash attention, XCD-sliced queues, NSPLIT=4
// Queue q = blockIdx.x & 7 owns units v in [6q, 6q+5] (unit v: h=v>>2, sp=v&3)
// -> each queue spans ~2 heads (~2 MB K/V+vT, fits the XCD's 4 MB L2).
// 192 items/queue, qb-descending; longest serial item = 16 tiles (critical path).
__global__ __launch_bounds__(256) void attn_kernel(const f16* __restrict__ qkv,
                                                   const f16* __restrict__ vT,
                                                   float* __restrict__ Opart,
                                                   float2* __restrict__ ml,
                                                   int* __restrict__ ctr) {
    __shared__ __align__(16) f16 Ks[64][72];   // [key][d]
    __shared__ __align__(16) f16 Vt[64][72];   // [d][key]
    __shared__ int s_item;
    const int t = threadIdx.x;
    const int wid = t >> 6;
    const int lane = t & 63;
    const int lr = lane & 15;
    const int quad = lane >> 4;
    const int srow = t >> 3;        // 0..31 (staging)
    const int scol = (t & 7) * 8;   // 0..56
    const int xq = blockIdx.x & 7;

    for (;;) {
        __syncthreads();
        if (t == 0) s_item = atomicAdd(&ctr[xq], 1);
        __syncthreads();
        const int item = s_item;
        if (item >= NQITEMS) return;
        const int qb = 31 - item / 6;
        const int v = xq * 6 + item % 6;     // unit 0..47
        const int h = v >> 2;
        const int sp = v & 3;
        const int q0 = qb * 128;

        const int nkb = 2 * qb + 2;
        const int chunk = (nkb + NSPLIT - 1) / NSPLIT;
        const int kb0 = sp * chunk;
        const int kb1 = min(nkb, kb0 + chunk);
        const int wrow0 = q0 + wid * 32;

        float m_i[2] = {-INFINITY, -INFINITY};
        float l_lane[2] = {0.f, 0.f};
        f32x4 zero = {0.f, 0.f, 0.f, 0.f};
        f32x4 o[4][2];
#pragma unroll
        for (int dt = 0; dt < 4; dt++)
#pragma unroll
            for (int qt = 0; qt < 2; qt++) o[dt][qt] = zero;

        f16x8 qf[2][2];
        int4 kreg[2], vreg[2];
        const f16* kbase = qkv + EMBED + (size_t)h * DHEAD;
        const f16* vbase = vT + (size_t)h * DHEAD * TSEQ;
        if (kb0 < kb1) {
#pragma unroll
            for (int qt = 0; qt < 2; qt++)
#pragma unroll
                for (int dh = 0; dh < 2; dh++)
                    qf[qt][dh] = *(const f16x8*)(qkv + (size_t)(wrow0 + qt * 16 + lr) * CQKV
                                                 + h * DHEAD + dh * 32 + quad * 8);
            const int k0 = kb0 * 64;
#pragma unroll
            for (int p = 0; p < 2; p++) {
                kreg[p] = *(const int4*)(kbase + (size_t)(k0 + p * 32 + srow) * CQKV + scol);
                vreg[p] = *(const int4*)(vbase + (size_t)(p * 32 + srow) * TSEQ + k0 + scol);
            }
        }

        for (int kb = kb0; kb < kb1; ++kb) {
            const int k0 = kb * 64;
            __syncthreads();
#pragma unroll
            for (int p = 0; p < 2; p++) {
                *(int4*)&Ks[p * 32 + srow][scol] = kreg[p];
                *(int4*)&Vt[p * 32 + srow][scol] = vreg[p];
            }
            __syncthreads();
            if (kb + 1 < kb1) {
                const int kn = (kb + 1) * 64;
#pragma unroll
                for (int p = 0; p < 2; p++) {
                    kreg[p] = *(const int4*)(kbase + (size_t)(kn + p * 32 + srow) * CQKV + scol);
                    vreg[p] = *(const int4*)(vbase + (size_t)(p * 32 + srow) * TSEQ + kn + scol);
                }
            }

            if (k0 <= wrow0 + 31) {   // wave-uniform compute guard (barriers always hit)
                f32x4 s[4][2];
#pragma unroll
                for (int kt = 0; kt < 4; kt++)
#pragma unroll
                    for (int qt = 0; qt < 2; qt++) s[kt][qt] = zero;
#pragma unroll
                for (int dh = 0; dh < 2; dh++) {
#pragma unroll
                    for (int kt = 0; kt < 4; kt++) {
                        f16x8 kf = *(const f16x8*)&Ks[kt * 16 + lr][dh * 32 + quad * 8];
#pragma unroll
                        for (int qt = 0; qt < 2; qt++)
                            s[kt][qt] = __builtin_amdgcn_mfma_f32_16x16x32_f16(kf, qf[qt][dh], s[kt][qt], 0, 0, 0);
                    }
                }
                if (k0 + 63 > wrow0) {
#pragma unroll
                    for (int kt = 0; kt < 4; kt++)
#pragma unroll
                        for (int qt = 0; qt < 2; qt++)
#pragma unroll
                            for (int r = 0; r < 4; r++) {
                                int key = k0 + kt * 16 + quad * 4 + r;
                                int row = wrow0 + qt * 16 + lr;
                                if (key > row) s[kt][qt][r] = -INFINITY;
                            }
                }
                float al[2];
#pragma unroll
                for (int qt = 0; qt < 2; qt++) {
                    float mx = -INFINITY;
#pragma unroll
                    for (int kt = 0; kt < 4; kt++)
#pragma unroll
                        for (int r = 0; r < 4; r++) mx = fmaxf(mx, s[kt][qt][r]);
                    mx = fmaxf(mx, __shfl_xor(mx, 16));
                    mx = fmaxf(mx, __shfl_xor(mx, 32));
                    float mn = fmaxf(m_i[qt], mx);
                    al[qt] = exp2f(m_i[qt] - mn);
                    m_i[qt] = mn;
                }
                union PW { f16x8 v8; f16x2 h2[4]; };
                PW pw[2][2];
                float rs[2] = {0.f, 0.f};
#pragma unroll
                for (int kt = 0; kt < 4; kt++)
#pragma unroll
                    for (int qt = 0; qt < 2; qt++) {
                        float p0 = exp2f(s[kt][qt][0] - m_i[qt]);
                        float p1 = exp2f(s[kt][qt][1] - m_i[qt]);
                        float p2 = exp2f(s[kt][qt][2] - m_i[qt]);
                        float p3 = exp2f(s[kt][qt][3] - m_i[qt]);
                        rs[qt] += (p0 + p1) + (p2 + p3);
                        pw[kt >> 1][qt].h2[(kt & 1) * 2]     = pkrtz(p0, p1);
                        pw[kt >> 1][qt].h2[(kt & 1) * 2 + 1] = pkrtz(p2, p3);
                    }
#pragma unroll
                for (int qt = 0; qt < 2; qt++) l_lane[qt] = l_lane[qt] * al[qt] + rs[qt];
#pragma unroll
                for (int dt = 0; dt < 4; dt++)
#pragma unroll
                    for (int qt = 0; qt < 2; qt++)
#pragma unroll
                        for (int r = 0; r < 4; r++) o[dt][qt][r] *= al[qt];
#pragma unroll
                for (int s2 = 0; s2 < 2; s2++)
#pragma unroll
                    for (int dt = 0; dt < 4; dt++) {
                        f16x4 vlo = *(const f16x4*)&Vt[dt * 16 + lr][s2 * 32 + quad * 4];
                        f16x4 vhi = *(const f16x4*)&Vt[dt * 16 + lr][s2 * 32 + quad * 4 + 16];
                        f16x8 vf;
#pragma unroll
                        for (int e = 0; e < 4; e++) { vf[e] = vlo[e]; vf[e + 4] = vhi[e]; }
#pragma unroll
                        for (int qt = 0; qt < 2; qt++)
                            o[dt][qt] = __builtin_amdgcn_mfma_f32_16x16x32_f16(vf, pw[s2][qt].v8, o[dt][qt], 0, 0, 0);
                    }
            }
        }

        float l_i[2];
#pragma unroll
        for (int qt = 0; qt < 2; qt++) {
            float v2 = l_lane[qt];
            v2 += __shfl_xor(v2, 16);
            v2 += __shfl_xor(v2, 32);
            l_i[qt] = v2;
        }
#pragma unroll
        for (int dt = 0; dt < 4; dt++)
#pragma unroll
            for (int qt = 0; qt < 2; qt++) {
                int row = wrow0 + qt * 16 + lr;
                float* dst = Opart + ((size_t)sp * TSEQ + row) * EMBED + h * DHEAD + dt * 16 + quad * 4;
                *(f32x4*)dst = o[dt][qt];
            }
#pragma unroll
        for (int qt = 0; qt < 2; qt++)
            if (quad == 0) {
                int row = wrow0 + qt * 16 + lr;
                ml[((size_t)sp * TSEQ + row) * NHEAD + h] = make_float2(m_i[qt], l_i[qt]);
            }
    }
}

// ---------------- merge split-K partials -> ctx f16
__global__ __launch_bounds__(256) void attn_merge_kernel(const float* __restrict__ Opart,
                                                         const float2* __restrict__ ml,
                                                         f16* __restrict__ ctx) {
    const int row = blockIdx.x;
    const int t = threadIdx.x;
    __shared__ float wgt[NSPLIT][NHEAD];
    if (t < NHEAD) {
        float m[NSPLIT], l[NSPLIT];
        float M = -INFINITY;
#pragma unroll
        for (int s = 0; s < NSPLIT; s++) {
            float2 v = ml[((size_t)s * TSEQ + row) * NHEAD + t];
            m[s] = v.x; l[s] = v.y;
            M = fmaxf(M, m[s]);
        }
        float L = 0.f;
        float w[NSPLIT];
#pragma unroll
        for (int s = 0; s < NSPLIT; s++) {
            w[s] = exp2f(m[s] - M);
            L += l[s] * w[s];
        }
        float rL = 1.0f / L;
#pragma unroll
        for (int s = 0; s < NSPLIT; s++) wgt[s][t] = w[s] * rL;
    }
    __syncthreads();
#pragma unroll
    for (int p = 0; p < 3; p++) {
        int c = t + p * 256;
        int h = c >> 6;
        float acc = 0.f;
#pragma unroll
        for (int s = 0; s < NSPLIT; s++)
            acc += wgt[s][h] * Opart[((size_t)s * TSEQ + row) * EMBED + c];
        ctx[(size_t)row * EMBED + c] = (f16)acc;
    }
}

extern "C" void kernel_launch(void* const* d_in, const int* in_sizes, int n_in,
                              void* d_out, int out_size, void* d_ws, size_t ws_size,
                              hipStream_t stream) {
    const float* x     = (const float*)d_in[0];
    const float* Wq    = (const float*)d_in[1];
    const float* bq    = (const float*)d_in[2];
    const float* Wk    = (const float*)d_in[3];
    const float* bk    = (const float*)d_in[4];
    const float* Wv    = (const float*)d_in[5];
    const float* bv    = (const float*)d_in[6];
    const float* Wo    = (const float*)d_in[7];
    const float* bo    = (const float*)d_in[8];
    const float* ln1_g = (const float*)d_in[9];
    const float* ln1_b = (const float*)d_in[10];
    const float* ln2_g = (const float*)d_in[11];
    const float* ln2_b = (const float*)d_in[12];
    const float* W1    = (const float*)d_in[13];
    const float* b1    = (const float*)d_in[14];
    const float* W2    = (const float*)d_in[15];
    const float* b2    = (const float*)d_in[16];

    char* p = (char*)d_ws;
    auto alloc = [&](size_t bytes) -> void* {
        void* r = (void*)p;
        p += (bytes + 255) & ~(size_t)255;
        return r;
    };
    f16*   WqkvT = (f16*)alloc((size_t)CQKV * EMBED * 2);
    f16*   WoT   = (f16*)alloc((size_t)EMBED * EMBED * 2);
    f16*   W1T   = (f16*)alloc((size_t)FFN_D * EMBED * 2);
    f16*   W2T   = (f16*)alloc((size_t)EMBED * FFN_D * 2);
    float* bqkv  = (float*)alloc((size_t)CQKV * 4);
    float* hf    = (float*)alloc((size_t)TSEQ * EMBED * 4);
    f16*   hh    = (f16*)alloc((size_t)TSEQ * EMBED * 2);
    f16*   qkv   = (f16*)alloc((size_t)TSEQ * CQKV * 2);
    f16*   vT    = (f16*)alloc((size_t)EMBED * TSEQ * 2);
    f16*   ctx   = (f16*)alloc((size_t)TSEQ * EMBED * 2);
    float* x2    = (float*)alloc((size_t)TSEQ * EMBED * 4);
    float* h2f   = (float*)alloc((size_t)TSEQ * EMBED * 4);
    f16*   h2h   = (f16*)alloc((size_t)TSEQ * EMBED * 2);
    f16*   m1    = (f16*)alloc((size_t)TSEQ * FFN_D * 2);
    int*   ctr   = (int*)alloc(256);

    // split-K attention partials ALIAS the post-attention buffers (x2..m1 span
    // 56.7 MB >= 50.3+1.6 MB; attention+merge complete before x2 is written)
    float*  Opart = x2;                                        // [NSPLIT][TSEQ][768] f32
    float2* mlbuf = (float2*)(x2 + (size_t)NSPLIT * TSEQ * EMBED);

    dim3 blk(256);
    // fused weight prep (6 transposes + bias concat, one launch)
    prep_kernel<<<dim3(6913), blk, 0, stream>>>(Wq, Wk, Wv, Wo, W1, W2, bq, bk, bv,
                                                WqkvT, WoT, W1T, W2T, bqkv);
    // LN1
    ln_kernel<<<dim3(TSEQ), blk, 0, stream>>>(x, ln1_g, ln1_b, hf, hh);
    // QKV fused GEMM (q section pre-scaled by SC2Q in epilogue)
    gemm_kernel<0, 128><<<dim3(CQKV / 128, TSEQ / 128), blk, 0, stream>>>(
        hh, WqkvT, bqkv, nullptr, nullptr, qkv, TSEQ, CQKV, EMBED);
    // V transpose for attention A-operand
    vtrans_kernel<<<dim3(TSEQ / 32, EMBED / 32), blk, 0, stream>>>(qkv, vT);
    // persistent attention (8 XCD-sliced queues, NSPLIT=4) + merge
    (void)hipMemsetAsync(ctr, 0, 256, stream);
    attn_kernel<<<dim3(1536), blk, 0, stream>>>(qkv, vT, Opart, mlbuf, ctr);
    attn_merge_kernel<<<dim3(TSEQ), blk, 0, stream>>>(Opart, mlbuf, ctx);
    // Wo GEMM + residual(h)  (overwrites the Opart alias region - partials are dead)
    gemm_kernel<1, 64><<<dim3(EMBED / 64, TSEQ / 128), blk, 0, stream>>>(
        ctx, WoT, bo, hf, x2, nullptr, TSEQ, EMBED, EMBED);
    // LN2
    ln_kernel<<<dim3(TSEQ), blk, 0, stream>>>(x2, ln2_g, ln2_b, h2f, h2h);
    // FFN1 + gelu
    gemm_kernel<2, 128><<<dim3(FFN_D / 128, TSEQ / 128), blk, 0, stream>>>(
        h2h, W1T, b1, nullptr, nullptr, m1, TSEQ, FFN_D, EMBED);
    // FFN2 + residual(h2) -> fp32 out
    gemm_kernel<1, 64><<<dim3(EMBED / 64, TSEQ / 128), blk, 0, stream>>>(
        m1, W2T, b2, h2f, (float*)d_out, nullptr, TSEQ, EMBED, FFN_D);
}

// Round 10
// 378.851 us; speedup vs baseline: 1.3098x; 1.0206x over previous
//
#include <hip/hip_runtime.h>
#include <math.h>

#define EMBED 768
#define FFN_D 3072
#define TSEQ 4096
#define NHEAD 12
#define DHEAD 64
#define CQKV 2304   // 3*EMBED
#define NSPLIT 4
#define NQITEMS 192                    // per XCD queue: 32 qb x 6 units
#define SC2Q 0.180336880111120419f     // 0.125 * log2(e), folded into Q in QKV epilogue

typedef _Float16 f16;
typedef __attribute__((ext_vector_type(2))) _Float16 f16x2;
typedef __attribute__((ext_vector_type(4))) _Float16 f16x4;
typedef __attribute__((ext_vector_type(8))) _Float16 f16x8;
typedef __attribute__((ext_vector_type(4))) float f32x4;

__device__ __forceinline__ f16x2 pkrtz(float a, float b) {
    return __builtin_bit_cast(f16x2, __builtin_amdgcn_cvt_pkrtz(a, b));
}

// async global->LDS, 16B per lane; lds base wave-uniform, lane i lands at base + i*16
__device__ __forceinline__ void gload16(const f16* g, f16* lds) {
    __builtin_amdgcn_global_load_lds((const __attribute__((address_space(1))) void*)g,
                                     (__attribute__((address_space(3))) void*)lds, 16, 0, 0);
}

// ---------------- fused weight prep: 6 transpose+convert passes + bias concat, ONE launch
__global__ __launch_bounds__(256) void prep_kernel(const float* __restrict__ Wq,
                                                   const float* __restrict__ Wk,
                                                   const float* __restrict__ Wv,
                                                   const float* __restrict__ Wo,
                                                   const float* __restrict__ W1,
                                                   const float* __restrict__ W2,
                                                   const float* __restrict__ bq,
                                                   const float* __restrict__ bk,
                                                   const float* __restrict__ bv,
                                                   f16* __restrict__ WqkvT,
                                                   f16* __restrict__ WoT,
                                                   f16* __restrict__ W1T,
                                                   f16* __restrict__ W2T,
                                                   float* __restrict__ bqkv) {
    const int b = blockIdx.x;
    const int t = threadIdx.x;
    if (b == 6912) {   // bias concat
#pragma unroll
        for (int i = 0; i < 9; i++) {
            int idx = i * 256 + t;
            if (idx < 768) bqkv[idx] = bq[idx];
            else if (idx < 1536) bqkv[idx] = bk[idx - 768];
            else if (idx < 2304) bqkv[idx] = bv[idx - 1536];
        }
        return;
    }
    const float* W; f16* WT; int din, dout, local;
    if (b < 576)       { W = Wq; WT = WqkvT;                         din = 768;  dout = 768;  local = b; }
    else if (b < 1152) { W = Wk; WT = WqkvT + 768 * 768;             din = 768;  dout = 768;  local = b - 576; }
    else if (b < 1728) { W = Wv; WT = WqkvT + 2 * 768 * 768;         din = 768;  dout = 768;  local = b - 1152; }
    else if (b < 2304) { W = Wo; WT = WoT;                           din = 768;  dout = 768;  local = b - 1728; }
    else if (b < 4608) { W = W1; WT = W1T;                           din = 768;  dout = 3072; local = b - 2304; }
    else               { W = W2; WT = W2T;                           din = 3072; dout = 768;  local = b - 4608; }
    const int tx2 = dout / 32;
    const int j0 = (local % tx2) * 32;
    const int i0 = (local / tx2) * 32;
    __shared__ float tile[32][33];
    const int tx = t & 31;
    const int ty = t >> 5;
#pragma unroll
    for (int rr = ty; rr < 32; rr += 8)
        tile[rr][tx] = W[(size_t)(i0 + rr) * dout + j0 + tx];
    __syncthreads();
#pragma unroll
    for (int rr = ty; rr < 32; rr += 8)
        WT[(size_t)(j0 + rr) * din + i0 + tx] = (f16)tile[tx][rr];
}

// ---------------- LayerNorm row kernel (768 wide), writes f16 only
__global__ __launch_bounds__(256) void ln_kernel(const float* __restrict__ x,
                                                 const float* __restrict__ g,
                                                 const float* __restrict__ b,
                                                 f16* __restrict__ hh) {
    const int row = blockIdx.x;
    const float* xr = x + (size_t)row * EMBED;
    const int t = threadIdx.x;
    float v0 = xr[t], v1 = xr[t + 256], v2 = xr[t + 512];
    float s = v0 + v1 + v2;
#pragma unroll
    for (int m = 1; m < 64; m <<= 1) s += __shfl_xor(s, m);
    __shared__ float red[4], red2[4];
    const int wid = t >> 6, lane = t & 63;
    if (lane == 0) red[wid] = s;
    __syncthreads();
    float mean = (red[0] + red[1] + red[2] + red[3]) * (1.0f / 768.0f);
    float d0 = v0 - mean, d1 = v1 - mean, d2 = v2 - mean;
    float ss = d0 * d0 + d1 * d1 + d2 * d2;
#pragma unroll
    for (int m = 1; m < 64; m <<= 1) ss += __shfl_xor(ss, m);
    if (lane == 0) red2[wid] = ss;
    __syncthreads();
    float inv = rsqrtf((red2[0] + red2[1] + red2[2] + red2[3]) * (1.0f / 768.0f) + 1e-5f);
    size_t base = (size_t)row * EMBED;
    hh[base + t]       = (f16)(d0 * inv * g[t] + b[t]);
    hh[base + t + 256] = (f16)(d1 * inv * g[t + 256] + b[t + 256]);
    hh[base + t + 512] = (f16)(d2 * inv * g[t + 512] + b[t + 512]);
}

// ---------------- GEMM: C[M][N] = A[M][K] * BT[N][K]^T + bias
// BK=64, XOR-swizzled LDS, global_load_lds staging, swapped MFMA operands.
// EPI 0: out fp16 (QKV: cols<768 scaled by SC2Q; cols>=1536 written TRANSPOSED to vtout)
// EPI 1: fp32 acc + bias + f16 residual     EPI 2: fp16 gelu(acc+bias)
template <int EPI, int BM, int BN>
__global__ __launch_bounds__(256) void gemm_kernel(const f16* __restrict__ A,
                                                   const f16* __restrict__ BT,
                                                   const float* __restrict__ bias,
                                                   const f16* __restrict__ resh,
                                                   float* __restrict__ outf,
                                                   f16* __restrict__ outh,
                                                   f16* __restrict__ vtout,
                                                   int M, int N, int K) {
    constexpr int IM = BM / 32;
    constexpr int JN = BN / 32;
    __shared__ __align__(16) f16 As[BM][64];
    __shared__ __align__(16) f16 Bs[BN][64];
    const int t = threadIdx.x;
    const int m0 = blockIdx.y * BM;
    const int n0 = blockIdx.x * BN;
    const int wid = t >> 6;
    const int lane = t & 63;
    const int wm = (wid >> 1) * (BM / 2);
    const int wn = (wid & 1) * (BN / 2);
    const int lr = lane & 15;
    const int quad = lane >> 4;
    const int sr = lane >> 3;            // 0..7 (row within an 8-row DMA call)
    const int scn = (lane & 7) ^ sr;     // swizzled source chunk (8 f16 per chunk)
    const int xv = lr & 7;               // read-side xor

    f32x4 zero = {0.f, 0.f, 0.f, 0.f};
    f32x4 acc[IM][JN];
#pragma unroll
    for (int i = 0; i < IM; i++)
#pragma unroll
        for (int j = 0; j < JN; j++) acc[i][j] = zero;

    const f16* Ap = A + (size_t)(m0 + wid * (BM / 4) + sr) * K + scn * 8;
    const f16* Bp = BT + (size_t)(n0 + wid * (BN / 4) + sr) * K + scn * 8;

    for (int k0 = 0; k0 < K; k0 += 64) {
        __syncthreads();
#pragma unroll
        for (int c = 0; c < BM / 32; c++)
            gload16(Ap + (size_t)(c * 8) * K + k0, &As[wid * (BM / 4) + c * 8][0]);
#pragma unroll
        for (int c = 0; c < BN / 32; c++)
            gload16(Bp + (size_t)(c * 8) * K + k0, &Bs[wid * (BN / 4) + c * 8][0]);
        __syncthreads();
#pragma unroll
        for (int ks = 0; ks < 2; ks++) {
            f16x8 af[IM], bf[JN];
#pragma unroll
            for (int i = 0; i < IM; i++)
                af[i] = *(const f16x8*)&As[wm + i * 16 + lr][((ks * 4 + quad) ^ xv) * 8];
#pragma unroll
            for (int j = 0; j < JN; j++)
                bf[j] = *(const f16x8*)&Bs[wn + j * 16 + lr][((ks * 4 + quad) ^ xv) * 8];
#pragma unroll
            for (int i = 0; i < IM; i++)
#pragma unroll
                for (int j = 0; j < JN; j++)
                    acc[i][j] = __builtin_amdgcn_mfma_f32_16x16x32_f16(bf[j], af[i], acc[i][j], 0, 0, 0);
        }
    }

    // acc[i][j][r] = C[row = m0+wm+i*16+lr][col = n0+wn+j*16+quad*4+r]
    const bool vsec = (EPI == 0) && (n0 >= 2 * EMBED);   // block-uniform (BN=128 aligned)
#pragma unroll
    for (int i = 0; i < IM; i++) {
        const int row = m0 + wm + i * 16 + lr;
#pragma unroll
        for (int j = 0; j < JN; j++) {
            const int col = n0 + wn + j * 16 + quad * 4;
            const float4 bv = *(const float4*)&bias[col];
            float v0 = acc[i][j][0] + bv.x;
            float v1 = acc[i][j][1] + bv.y;
            float v2 = acc[i][j][2] + bv.z;
            float v3 = acc[i][j][3] + bv.w;
            const size_t idx = (size_t)row * N + col;
            if (EPI == 0) {
                if (vsec) {   // V section -> transposed vT[(col-1536)][row]
                    const int c0 = col - 2 * EMBED;
                    vtout[(size_t)(c0 + 0) * TSEQ + row] = (f16)v0;
                    vtout[(size_t)(c0 + 1) * TSEQ + row] = (f16)v1;
                    vtout[(size_t)(c0 + 2) * TSEQ + row] = (f16)v2;
                    vtout[(size_t)(c0 + 3) * TSEQ + row] = (f16)v3;
                } else {
                    const float qs = (col < EMBED) ? SC2Q : 1.0f;
                    f16x4 hv = {(f16)(v0 * qs), (f16)(v1 * qs), (f16)(v2 * qs), (f16)(v3 * qs)};
                    *(f16x4*)&outh[idx] = hv;
                }
            } else if (EPI == 1) {
                const f16x4 rr = *(const f16x4*)&resh[idx];
                f32x4 ov = {v0 + (float)rr[0], v1 + (float)rr[1], v2 + (float)rr[2], v3 + (float)rr[3]};
                *(f32x4*)&outf[idx] = ov;
            } else {
                f16x4 hv = {(f16)(0.5f * v0 * (1.0f + erff(v0 * 0.70710678118654752f))),
                            (f16)(0.5f * v1 * (1.0f + erff(v1 * 0.70710678118654752f))),
                            (f16)(0.5f * v2 * (1.0f + erff(v2 * 0.70710678118654752f))),
                            (f16)(0.5f * v3 * (1.0f + erff(v3 * 0.70710678118654752f)))};
                *(f16x4*)&outh[idx] = hv;
            }
        }
    }
}

// ---------------- persistent flash attention, XCD-sliced queues, NSPLIT=4
// 128-key staging per barrier-pair (2 softmax passes per stage -> half the barriers).
// f16 unnormalized partials. Queue q = blockIdx.x & 7 owns units [6q, 6q+5].
__global__ __launch_bounds__(256) void attn_kernel(const f16* __restrict__ qkv,
                                                   const f16* __restrict__ vT,
                                                   f16* __restrict__ OpartH,
                                                   float2* __restrict__ ml,
                                                   int* __restrict__ ctr) {
    __shared__ __align__(16) f16 Ks[128][72];    // [key 0..127][d]
    __shared__ __align__(16) f16 Vt[64][136];    // [d][key 0..127]
    __shared__ int s_item;
    const int t = threadIdx.x;
    const int wid = t >> 6;
    const int lane = t & 63;
    const int lr = lane & 15;
    const int quad = lane >> 4;
    const int kr = t >> 3;          // K staging: row within 32-row pass
    const int kc = (t & 7) * 8;     // K staging: d offset
    const int vr = t >> 4;          // V staging: d-row within 16-row pass
    const int vc = (t & 15) * 8;    // V staging: key offset (128 keys = 16 chunks)
    const int xq = blockIdx.x & 7;

    for (;;) {
        __syncthreads();
        if (t == 0) s_item = atomicAdd(&ctr[xq], 1);
        __syncthreads();
        const int item = s_item;
        if (item >= NQITEMS) return;
        const int qb = 31 - item / 6;
        const int u = xq * 6 + item % 6;     // unit 0..47
        const int h = u >> 2;
        const int sp = u & 3;
        const int q0 = qb * 128;

        const int nkb = 2 * qb + 2;
        const int chunk = (nkb + NSPLIT - 1) / NSPLIT;
        const int kb0 = sp * chunk;
        const int kb1 = min(nkb, kb0 + chunk);
        const int wrow0 = q0 + wid * 32;

        float m_i[2] = {-INFINITY, -INFINITY};
        float l_lane[2] = {0.f, 0.f};
        f32x4 zero = {0.f, 0.f, 0.f, 0.f};
        f32x4 o[4][2];
#pragma unroll
        for (int dt = 0; dt < 4; dt++)
#pragma unroll
            for (int qt = 0; qt < 2; qt++) o[dt][qt] = zero;

        f16x8 qf[2][2];
        int4 kreg[4], vreg[4];
        const f16* kbase = qkv + EMBED + (size_t)h * DHEAD;
        const f16* vbase = vT + (size_t)h * DHEAD * TSEQ;
        if (kb0 < kb1) {
#pragma unroll
            for (int qt = 0; qt < 2; qt++)
#pragma unroll
                for (int dh = 0; dh < 2; dh++)
                    qf[qt][dh] = *(const f16x8*)(qkv + (size_t)(wrow0 + qt * 16 + lr) * CQKV
                                                 + h * DHEAD + dh * 32 + quad * 8);
            const int k0 = kb0 * 64;
#pragma unroll
            for (int p = 0; p < 4; p++) {
                int krow = min(k0 + p * 32 + kr, TSEQ - 1);
                kreg[p] = *(const int4*)(kbase + (size_t)krow * CQKV + kc);
                int vkey = min(k0 + vc, TSEQ - 8);
                vreg[p] = *(const int4*)(vbase + (size_t)(p * 16 + vr) * TSEQ + vkey);
            }
        }

        for (int kb = kb0; kb < kb1; kb += 2) {
            __syncthreads();
#pragma unroll
            for (int p = 0; p < 4; p++) {
                *(int4*)&Ks[p * 32 + kr][kc] = kreg[p];
                *(int4*)&Vt[p * 16 + vr][vc] = vreg[p];
            }
            __syncthreads();
            if (kb + 2 < kb1) {   // prefetch next 128-key stage (overlaps compute)
                const int kn = (kb + 2) * 64;
#pragma unroll
                for (int p = 0; p < 4; p++) {
                    int krow = min(kn + p * 32 + kr, TSEQ - 1);
                    kreg[p] = *(const int4*)(kbase + (size_t)krow * CQKV + kc);
                    int vkey = min(kn + vc, TSEQ - 8);
                    vreg[p] = *(const int4*)(vbase + (size_t)(p * 16 + vr) * TSEQ + vkey);
                }
            }

#pragma unroll
            for (int half = 0; half < 2; half++) {   // no barriers inside: per-wave break OK
                const int kbh = kb + half;
                if (kbh >= kb1) break;
                const int k0h = kbh * 64;
                if (k0h > wrow0 + 31) break;   // causal: later halves only larger
                const int kofs = half * 64;

                f32x4 s[4][2];
#pragma unroll
                for (int kt = 0; kt < 4; kt++)
#pragma unroll
                    for (int qt = 0; qt < 2; qt++) s[kt][qt] = zero;
#pragma unroll
                for (int dh = 0; dh < 2; dh++) {
#pragma unroll
                    for (int kt = 0; kt < 4; kt++) {
                        f16x8 kf = *(const f16x8*)&Ks[kofs + kt * 16 + lr][dh * 32 + quad * 8];
#pragma unroll
                        for (int qt = 0; qt < 2; qt++)
                            s[kt][qt] = __builtin_amdgcn_mfma_f32_16x16x32_f16(kf, qf[qt][dh], s[kt][qt], 0, 0, 0);
                    }
                }
                if (k0h + 63 > wrow0) {
#pragma unroll
                    for (int kt = 0; kt < 4; kt++)
#pragma unroll
                        for (int qt = 0; qt < 2; qt++)
#pragma unroll
                            for (int r = 0; r < 4; r++) {
                                int key = k0h + kt * 16 + quad * 4 + r;
                                int row = wrow0 + qt * 16 + lr;
                                if (key > row) s[kt][qt][r] = -INFINITY;
                            }
                }
                float al[2];
#pragma unroll
                for (int qt = 0; qt < 2; qt++) {
                    float mx = -INFINITY;
#pragma unroll
                    for (int kt = 0; kt < 4; kt++)
#pragma unroll
                        for (int r = 0; r < 4; r++) mx = fmaxf(mx, s[kt][qt][r]);
                    mx = fmaxf(mx, __shfl_xor(mx, 16));
                    mx = fmaxf(mx, __shfl_xor(mx, 32));
                    float mn = fmaxf(m_i[qt], mx);
                    al[qt] = exp2f(m_i[qt] - mn);
                    m_i[qt] = mn;
                }
                union PW { f16x8 v8; f16x2 h2[4]; };
                PW pw[2][2];
                float rs[2] = {0.f, 0.f};
#pragma unroll
                for (int kt = 0; kt < 4; kt++)
#pragma unroll
                    for (int qt = 0; qt < 2; qt++) {
                        float p0 = exp2f(s[kt][qt][0] - m_i[qt]);
                        float p1 = exp2f(s[kt][qt][1] - m_i[qt]);
                        float p2 = exp2f(s[kt][qt][2] - m_i[qt]);
                        float p3 = exp2f(s[kt][qt][3] - m_i[qt]);
                        rs[qt] += (p0 + p1) + (p2 + p3);
                        pw[kt >> 1][qt].h2[(kt & 1) * 2]     = pkrtz(p0, p1);
                        pw[kt >> 1][qt].h2[(kt & 1) * 2 + 1] = pkrtz(p2, p3);
                    }
#pragma unroll
                for (int qt = 0; qt < 2; qt++) l_lane[qt] = l_lane[qt] * al[qt] + rs[qt];
#pragma unroll
                for (int dt = 0; dt < 4; dt++)
#pragma unroll
                    for (int qt = 0; qt < 2; qt++)
#pragma unroll
                        for (int r = 0; r < 4; r++) o[dt][qt][r] *= al[qt];
#pragma unroll
                for (int s2 = 0; s2 < 2; s2++)
#pragma unroll
                    for (int dt = 0; dt < 4; dt++) {
                        f16x4 vlo = *(const f16x4*)&Vt[dt * 16 + lr][kofs + s2 * 32 + quad * 4];
                        f16x4 vhi = *(const f16x4*)&Vt[dt * 16 + lr][kofs + s2 * 32 + quad * 4 + 16];
                        f16x8 vf;
#pragma unroll
                        for (int e = 0; e < 4; e++) { vf[e] = vlo[e]; vf[e + 4] = vhi[e]; }
#pragma unroll
                        for (int qt = 0; qt < 2; qt++)
                            o[dt][qt] = __builtin_amdgcn_mfma_f32_16x16x32_f16(vf, pw[s2][qt].v8, o[dt][qt], 0, 0, 0);
                    }
            }
        }

        float l_i[2];
#pragma unroll
        for (int qt = 0; qt < 2; qt++) {
            float v2 = l_lane[qt];
            v2 += __shfl_xor(v2, 16);
            v2 += __shfl_xor(v2, 32);
            l_i[qt] = v2;
        }
#pragma unroll
        for (int dt = 0; dt < 4; dt++)
#pragma unroll
            for (int qt = 0; qt < 2; qt++) {
                int row = wrow0 + qt * 16 + lr;
                f16x4 oh = {(f16)o[dt][qt][0], (f16)o[dt][qt][1], (f16)o[dt][qt][2], (f16)o[dt][qt][3]};
                *(f16x4*)&OpartH[((size_t)sp * TSEQ + row) * EMBED + h * DHEAD + dt * 16 + quad * 4] = oh;
            }
#pragma unroll
        for (int qt = 0; qt < 2; qt++)
            if (quad == 0) {
                int row = wrow0 + qt * 16 + lr;
                ml[((size_t)sp * TSEQ + row) * NHEAD + h] = make_float2(m_i[qt], l_i[qt]);
            }
    }
}

// ---------------- merge split-K f16 partials -> ctx f16
__global__ __launch_bounds__(256) void attn_merge_kernel(const f16* __restrict__ OpartH,
                                                         const float2* __restrict__ ml,
                                                         f16* __restrict__ ctx) {
    const int row = blockIdx.x;
    const int t = threadIdx.x;
    __shared__ float wgt[NSPLIT][NHEAD];
    if (t < NHEAD) {
        float m[NSPLIT], l[NSPLIT];
        float M = -INFINITY;
#pragma unroll
        for (int s = 0; s < NSPLIT; s++) {
            float2 v = ml[((size_t)s * TSEQ + row) * NHEAD + t];
            m[s] = v.x; l[s] = v.y;
            M = fmaxf(M, m[s]);
        }
        float L = 0.f;
        float w[NSPLIT];
#pragma unroll
        for (int s = 0; s < NSPLIT; s++) {
            w[s] = exp2f(m[s] - M);
            L += l[s] * w[s];
        }
        float rL = 1.0f / L;
#pragma unroll
        for (int s = 0; s < NSPLIT; s++) wgt[s][t] = w[s] * rL;
    }
    __syncthreads();
#pragma unroll
    for (int p = 0; p < 3; p++) {
        int c = t + p * 256;
        int h = c >> 6;
        float acc = 0.f;
#pragma unroll
        for (int s = 0; s < NSPLIT; s++)
            acc += wgt[s][h] * (float)OpartH[((size_t)s * TSEQ + row) * EMBED + c];
        ctx[(size_t)row * EMBED + c] = (f16)acc;
    }
}

extern "C" void kernel_launch(void* const* d_in, const int* in_sizes, int n_in,
                              void* d_out, int out_size, void* d_ws, size_t ws_size,
                              hipStream_t stream) {
    const float* x     = (const float*)d_in[0];
    const float* Wq    = (const float*)d_in[1];
    const float* bq    = (const float*)d_in[2];
    const float* Wk    = (const float*)d_in[3];
    const float* bk    = (const float*)d_in[4];
    const float* Wv    = (const float*)d_in[5];
    const float* bv    = (const float*)d_in[6];
    const float* Wo    = (const float*)d_in[7];
    const float* bo    = (const float*)d_in[8];
    const float* ln1_g = (const float*)d_in[9];
    const float* ln1_b = (const float*)d_in[10];
    const float* ln2_g = (const float*)d_in[11];
    const float* ln2_b = (const float*)d_in[12];
    const float* W1    = (const float*)d_in[13];
    const float* b1    = (const float*)d_in[14];
    const float* W2    = (const float*)d_in[15];
    const float* b2    = (const float*)d_in[16];

    char* p = (char*)d_ws;
    auto alloc = [&](size_t bytes) -> void* {
        void* r = (void*)p;
        p += (bytes + 255) & ~(size_t)255;
        return r;
    };
    f16*   WqkvT = (f16*)alloc((size_t)CQKV * EMBED * 2);
    f16*   WoT   = (f16*)alloc((size_t)EMBED * EMBED * 2);
    f16*   W1T   = (f16*)alloc((size_t)FFN_D * EMBED * 2);
    f16*   W2T   = (f16*)alloc((size_t)EMBED * FFN_D * 2);
    float* bqkv  = (float*)alloc((size_t)CQKV * 4);
    f16*   hh    = (f16*)alloc((size_t)TSEQ * EMBED * 2);
    f16*   qkv   = (f16*)alloc((size_t)TSEQ * CQKV * 2);   // V third unused (vT direct)
    f16*   vT    = (f16*)alloc((size_t)EMBED * TSEQ * 2);
    f16*   ctx   = (f16*)alloc((size_t)TSEQ * EMBED * 2);
    float* x2    = (float*)alloc((size_t)TSEQ * EMBED * 4);
    f16*   h2h   = (f16*)alloc((size_t)TSEQ * EMBED * 2);
    f16*   m1    = (f16*)alloc((size_t)TSEQ * FFN_D * 2);
    int*   ctr   = (int*)alloc(256);

    // aliases (lifetime-disjoint):
    //   OpartH (25.2 MB f16) = m1 region  (attn+merge finish before FFN1 writes m1)
    //   mlbuf  (1.5 MB)      = x2 region  (merge reads before Wo writes x2)
    f16*    OpartH = m1;
    float2* mlbuf  = (float2*)x2;

    dim3 blk(256);
    prep_kernel<<<dim3(6913), blk, 0, stream>>>(Wq, Wk, Wv, Wo, W1, W2, bq, bk, bv,
                                                WqkvT, WoT, W1T, W2T, bqkv);
    // LN1 -> hh (f16)
    ln_kernel<<<dim3(TSEQ), blk, 0, stream>>>(x, ln1_g, ln1_b, hh);
    // QKV fused GEMM: q scaled by SC2Q; V section written transposed to vT
    gemm_kernel<0, 128, 128><<<dim3(CQKV / 128, TSEQ / 128), blk, 0, stream>>>(
        hh, WqkvT, bqkv, nullptr, nullptr, qkv, vT, TSEQ, CQKV, EMBED);
    // persistent attention (8 XCD queues, NSPLIT=4, 128-key stages) + merge
    (void)hipMemsetAsync(ctr, 0, 256, stream);
    attn_kernel<<<dim3(1536), blk, 0, stream>>>(qkv, vT, OpartH, mlbuf, ctr);
    attn_merge_kernel<<<dim3(TSEQ), blk, 0, stream>>>(OpartH, mlbuf, ctx);
    // Wo GEMM + f16 residual(hh) -> fp32 x2 (overwrites mlbuf alias - dead)
    gemm_kernel<1, 128, 64><<<dim3(EMBED / 64, TSEQ / 128), blk, 0, stream>>>(
        ctx, WoT, bo, hh, x2, nullptr, nullptr, TSEQ, EMBED, EMBED);
    // LN2 -> h2h (f16)
    ln_kernel<<<dim3(TSEQ), blk, 0, stream>>>(x2, ln2_g, ln2_b, h2h);
    // FFN1 + gelu -> m1 (overwrites OpartH alias - dead)
    gemm_kernel<2, 128, 128><<<dim3(FFN_D / 128, TSEQ / 128), blk, 0, stream>>>(
        h2h, W1T, b1, nullptr, nullptr, m1, nullptr, TSEQ, FFN_D, EMBED);
    // FFN2 + f16 residual(h2h) -> fp32 d_out
    gemm_kernel<1, 128, 64><<<dim3(EMBED / 64, TSEQ / 128), blk, 0, stream>>>(
        m1, W2T, b2, h2h, (float*)d_out, nullptr, nullptr, TSEQ, EMBED, FFN_D);
}

// Round 11
// 371.835 us; speedup vs baseline: 1.3345x; 1.0189x over previous
//
#include <hip/hip_runtime.h>
#include <math.h>

#define EMBED 768
#define FFN_D 3072
#define TSEQ 4096
#define NHEAD 12
#define DHEAD 64
#define CQKV 2304   // 3*EMBED
#define NSPLIT 4
#define NQITEMS 192                    // per XCD queue: 32 qb x 6 units
#define SC2Q 0.180336880111120419f     // 0.125 * log2(e), folded into Q in QKV epilogue

typedef _Float16 f16;
typedef __attribute__((ext_vector_type(2))) _Float16 f16x2;
typedef __attribute__((ext_vector_type(4))) _Float16 f16x4;
typedef __attribute__((ext_vector_type(8))) _Float16 f16x8;
typedef __attribute__((ext_vector_type(4))) float f32x4;

__device__ __forceinline__ f16x2 pkrtz(float a, float b) {
    return __builtin_bit_cast(f16x2, __builtin_amdgcn_cvt_pkrtz(a, b));
}

// async global->LDS, 16B per lane; lds base wave-uniform, lane i lands at base + i*16
__device__ __forceinline__ void gload16(const f16* g, f16* lds) {
    __builtin_amdgcn_global_load_lds((const __attribute__((address_space(1))) void*)g,
                                     (__attribute__((address_space(3))) void*)lds, 16, 0, 0);
}

// ---------------- fused weight prep: 6 transpose+convert passes + bias concat, ONE launch
__global__ __launch_bounds__(256) void prep_kernel(const float* __restrict__ Wq,
                                                   const float* __restrict__ Wk,
                                                   const float* __restrict__ Wv,
                                                   const float* __restrict__ Wo,
                                                   const float* __restrict__ W1,
                                                   const float* __restrict__ W2,
                                                   const float* __restrict__ bq,
                                                   const float* __restrict__ bk,
                                                   const float* __restrict__ bv,
                                                   f16* __restrict__ WqkvT,
                                                   f16* __restrict__ WoT,
                                                   f16* __restrict__ W1T,
                                                   f16* __restrict__ W2T,
                                                   float* __restrict__ bqkv) {
    const int b = blockIdx.x;
    const int t = threadIdx.x;
    if (b == 6912) {   // bias concat
#pragma unroll
        for (int i = 0; i < 9; i++) {
            int idx = i * 256 + t;
            if (idx < 768) bqkv[idx] = bq[idx];
            else if (idx < 1536) bqkv[idx] = bk[idx - 768];
            else if (idx < 2304) bqkv[idx] = bv[idx - 1536];
        }
        return;
    }
    const float* W; f16* WT; int din, dout, local;
    if (b < 576)       { W = Wq; WT = WqkvT;                         din = 768;  dout = 768;  local = b; }
    else if (b < 1152) { W = Wk; WT = WqkvT + 768 * 768;             din = 768;  dout = 768;  local = b - 576; }
    else if (b < 1728) { W = Wv; WT = WqkvT + 2 * 768 * 768;         din = 768;  dout = 768;  local = b - 1152; }
    else if (b < 2304) { W = Wo; WT = WoT;                           din = 768;  dout = 768;  local = b - 1728; }
    else if (b < 4608) { W = W1; WT = W1T;                           din = 768;  dout = 3072; local = b - 2304; }
    else               { W = W2; WT = W2T;                           din = 3072; dout = 768;  local = b - 4608; }
    const int tx2 = dout / 32;
    const int j0 = (local % tx2) * 32;
    const int i0 = (local / tx2) * 32;
    __shared__ float tile[32][33];
    const int tx = t & 31;
    const int ty = t >> 5;
#pragma unroll
    for (int rr = ty; rr < 32; rr += 8)
        tile[rr][tx] = W[(size_t)(i0 + rr) * dout + j0 + tx];
    __syncthreads();
#pragma unroll
    for (int rr = ty; rr < 32; rr += 8)
        WT[(size_t)(j0 + rr) * din + i0 + tx] = (f16)tile[tx][rr];
}

// ---------------- LayerNorm row kernel (768 wide), writes f16 only
__global__ __launch_bounds__(256) void ln_kernel(const float* __restrict__ x,
                                                 const float* __restrict__ g,
                                                 const float* __restrict__ b,
                                                 f16* __restrict__ hh) {
    const int row = blockIdx.x;
    const float* xr = x + (size_t)row * EMBED;
    const int t = threadIdx.x;
    float v0 = xr[t], v1 = xr[t + 256], v2 = xr[t + 512];
    float s = v0 + v1 + v2;
#pragma unroll
    for (int m = 1; m < 64; m <<= 1) s += __shfl_xor(s, m);
    __shared__ float red[4], red2[4];
    const int wid = t >> 6, lane = t & 63;
    if (lane == 0) red[wid] = s;
    __syncthreads();
    float mean = (red[0] + red[1] + red[2] + red[3]) * (1.0f / 768.0f);
    float d0 = v0 - mean, d1 = v1 - mean, d2 = v2 - mean;
    float ss = d0 * d0 + d1 * d1 + d2 * d2;
#pragma unroll
    for (int m = 1; m < 64; m <<= 1) ss += __shfl_xor(ss, m);
    if (lane == 0) red2[wid] = ss;
    __syncthreads();
    float inv = rsqrtf((red2[0] + red2[1] + red2[2] + red2[3]) * (1.0f / 768.0f) + 1e-5f);
    size_t base = (size_t)row * EMBED;
    hh[base + t]       = (f16)(d0 * inv * g[t] + b[t]);
    hh[base + t + 256] = (f16)(d1 * inv * g[t + 256] + b[t + 256]);
    hh[base + t + 512] = (f16)(d2 * inv * g[t + 512] + b[t + 512]);
}

// ---------------- GEMM: C[M][N] = A[M][K] * BT[N][K]^T + bias
// BK=64, XOR-swizzled LDS, global_load_lds staging, swapped MFMA operands.
// EPI 0: out fp16 (QKV: cols<768 scaled by SC2Q; cols>=1536 written TRANSPOSED to vtout)
// EPI 1: fp32 acc + bias + f16 residual     EPI 2: fp16 gelu(acc+bias)
template <int EPI, int BM, int BN>
__global__ __launch_bounds__(256) void gemm_kernel(const f16* __restrict__ A,
                                                   const f16* __restrict__ BT,
                                                   const float* __restrict__ bias,
                                                   const f16* __restrict__ resh,
                                                   float* __restrict__ outf,
                                                   f16* __restrict__ outh,
                                                   f16* __restrict__ vtout,
                                                   int M, int N, int K) {
    constexpr int IM = BM / 32;
    constexpr int JN = BN / 32;
    __shared__ __align__(16) f16 As[BM][64];
    __shared__ __align__(16) f16 Bs[BN][64];
    const int t = threadIdx.x;
    const int m0 = blockIdx.y * BM;
    const int n0 = blockIdx.x * BN;
    const int wid = t >> 6;
    const int lane = t & 63;
    const int wm = (wid >> 1) * (BM / 2);
    const int wn = (wid & 1) * (BN / 2);
    const int lr = lane & 15;
    const int quad = lane >> 4;
    const int sr = lane >> 3;            // 0..7 (row within an 8-row DMA call)
    const int scn = (lane & 7) ^ sr;     // swizzled source chunk (8 f16 per chunk)
    const int xv = lr & 7;               // read-side xor

    f32x4 zero = {0.f, 0.f, 0.f, 0.f};
    f32x4 acc[IM][JN];
#pragma unroll
    for (int i = 0; i < IM; i++)
#pragma unroll
        for (int j = 0; j < JN; j++) acc[i][j] = zero;

    const f16* Ap = A + (size_t)(m0 + wid * (BM / 4) + sr) * K + scn * 8;
    const f16* Bp = BT + (size_t)(n0 + wid * (BN / 4) + sr) * K + scn * 8;

    for (int k0 = 0; k0 < K; k0 += 64) {
        __syncthreads();
#pragma unroll
        for (int c = 0; c < BM / 32; c++)
            gload16(Ap + (size_t)(c * 8) * K + k0, &As[wid * (BM / 4) + c * 8][0]);
#pragma unroll
        for (int c = 0; c < BN / 32; c++)
            gload16(Bp + (size_t)(c * 8) * K + k0, &Bs[wid * (BN / 4) + c * 8][0]);
        __syncthreads();
#pragma unroll
        for (int ks = 0; ks < 2; ks++) {
            f16x8 af[IM], bf[JN];
#pragma unroll
            for (int i = 0; i < IM; i++)
                af[i] = *(const f16x8*)&As[wm + i * 16 + lr][((ks * 4 + quad) ^ xv) * 8];
#pragma unroll
            for (int j = 0; j < JN; j++)
                bf[j] = *(const f16x8*)&Bs[wn + j * 16 + lr][((ks * 4 + quad) ^ xv) * 8];
#pragma unroll
            for (int i = 0; i < IM; i++)
#pragma unroll
                for (int j = 0; j < JN; j++)
                    acc[i][j] = __builtin_amdgcn_mfma_f32_16x16x32_f16(bf[j], af[i], acc[i][j], 0, 0, 0);
        }
    }

    // acc[i][j][r] = C[row = m0+wm+i*16+lr][col = n0+wn+j*16+quad*4+r]
    const bool vsec = (EPI == 0) && (n0 >= 2 * EMBED);   // block-uniform (BN=128 aligned)
#pragma unroll
    for (int i = 0; i < IM; i++) {
        const int row = m0 + wm + i * 16 + lr;
#pragma unroll
        for (int j = 0; j < JN; j++) {
            const int col = n0 + wn + j * 16 + quad * 4;
            const float4 bv = *(const float4*)&bias[col];
            float v0 = acc[i][j][0] + bv.x;
            float v1 = acc[i][j][1] + bv.y;
            float v2 = acc[i][j][2] + bv.z;
            float v3 = acc[i][j][3] + bv.w;
            const size_t idx = (size_t)row * N + col;
            if (EPI == 0) {
                if (vsec) {   // V section -> transposed vT[(col-1536)][row]
                    const int c0 = col - 2 * EMBED;
                    vtout[(size_t)(c0 + 0) * TSEQ + row] = (f16)v0;
                    vtout[(size_t)(c0 + 1) * TSEQ + row] = (f16)v1;
                    vtout[(size_t)(c0 + 2) * TSEQ + row] = (f16)v2;
                    vtout[(size_t)(c0 + 3) * TSEQ + row] = (f16)v3;
                } else {
                    const float qs = (col < EMBED) ? SC2Q : 1.0f;
                    f16x4 hv = {(f16)(v0 * qs), (f16)(v1 * qs), (f16)(v2 * qs), (f16)(v3 * qs)};
                    *(f16x4*)&outh[idx] = hv;
                }
            } else if (EPI == 1) {
                const f16x4 rr = *(const f16x4*)&resh[idx];
                f32x4 ov = {v0 + (float)rr[0], v1 + (float)rr[1], v2 + (float)rr[2], v3 + (float)rr[3]};
                *(f32x4*)&outf[idx] = ov;
            } else {
                f16x4 hv = {(f16)(0.5f * v0 * (1.0f + erff(v0 * 0.70710678118654752f))),
                            (f16)(0.5f * v1 * (1.0f + erff(v1 * 0.70710678118654752f))),
                            (f16)(0.5f * v2 * (1.0f + erff(v2 * 0.70710678118654752f))),
                            (f16)(0.5f * v3 * (1.0f + erff(v3 * 0.70710678118654752f)))};
                *(f16x4*)&outh[idx] = hv;
            }
        }
    }
}

// ---------------- persistent flash attention, XCD-sliced queues, NSPLIT=4
// 64-key staging (R9 structure: 18.9 KB LDS, kreg[2]/vreg[2] prefetch) + f16 partials.
// Queue q = blockIdx.x & 7 owns units v in [6q, 6q+5] (unit v: h=v>>2, sp=v&3).
__global__ __launch_bounds__(256) void attn_kernel(const f16* __restrict__ qkv,
                                                   const f16* __restrict__ vT,
                                                   f16* __restrict__ OpartH,
                                                   float2* __restrict__ ml,
                                                   int* __restrict__ ctr) {
    __shared__ __align__(16) f16 Ks[64][72];   // [key][d]
    __shared__ __align__(16) f16 Vt[64][72];   // [d][key]
    __shared__ int s_item;
    const int t = threadIdx.x;
    const int wid = t >> 6;
    const int lane = t & 63;
    const int lr = lane & 15;
    const int quad = lane >> 4;
    const int srow = t >> 3;        // 0..31 (staging)
    const int scol = (t & 7) * 8;   // 0..56
    const int xq = blockIdx.x & 7;

    for (;;) {
        __syncthreads();
        if (t == 0) s_item = atomicAdd(&ctr[xq], 1);
        __syncthreads();
        const int item = s_item;
        if (item >= NQITEMS) return;
        const int qb = 31 - item / 6;
        const int u = xq * 6 + item % 6;     // unit 0..47
        const int h = u >> 2;
        const int sp = u & 3;
        const int q0 = qb * 128;

        const int nkb = 2 * qb + 2;
        const int chunk = (nkb + NSPLIT - 1) / NSPLIT;
        const int kb0 = sp * chunk;
        const int kb1 = min(nkb, kb0 + chunk);
        const int wrow0 = q0 + wid * 32;

        float m_i[2] = {-INFINITY, -INFINITY};
        float l_lane[2] = {0.f, 0.f};
        f32x4 zero = {0.f, 0.f, 0.f, 0.f};
        f32x4 o[4][2];
#pragma unroll
        for (int dt = 0; dt < 4; dt++)
#pragma unroll
            for (int qt = 0; qt < 2; qt++) o[dt][qt] = zero;

        f16x8 qf[2][2];
        int4 kreg[2], vreg[2];
        const f16* kbase = qkv + EMBED + (size_t)h * DHEAD;
        const f16* vbase = vT + (size_t)h * DHEAD * TSEQ;
        if (kb0 < kb1) {
#pragma unroll
            for (int qt = 0; qt < 2; qt++)
#pragma unroll
                for (int dh = 0; dh < 2; dh++)
                    qf[qt][dh] = *(const f16x8*)(qkv + (size_t)(wrow0 + qt * 16 + lr) * CQKV
                                                 + h * DHEAD + dh * 32 + quad * 8);
            const int k0 = kb0 * 64;
#pragma unroll
            for (int p = 0; p < 2; p++) {
                kreg[p] = *(const int4*)(kbase + (size_t)(k0 + p * 32 + srow) * CQKV + scol);
                vreg[p] = *(const int4*)(vbase + (size_t)(p * 32 + srow) * TSEQ + k0 + scol);
            }
        }

        for (int kb = kb0; kb < kb1; ++kb) {
            const int k0 = kb * 64;
            __syncthreads();
#pragma unroll
            for (int p = 0; p < 2; p++) {
                *(int4*)&Ks[p * 32 + srow][scol] = kreg[p];
                *(int4*)&Vt[p * 32 + srow][scol] = vreg[p];
            }
            __syncthreads();
            if (kb + 1 < kb1) {
                const int kn = (kb + 1) * 64;
#pragma unroll
                for (int p = 0; p < 2; p++) {
                    kreg[p] = *(const int4*)(kbase + (size_t)(kn + p * 32 + srow) * CQKV + scol);
                    vreg[p] = *(const int4*)(vbase + (size_t)(p * 32 + srow) * TSEQ + kn + scol);
                }
            }

            if (k0 <= wrow0 + 31) {   // wave-uniform compute guard (barriers always hit)
                f32x4 s[4][2];
#pragma unroll
                for (int kt = 0; kt < 4; kt++)
#pragma unroll
                    for (int qt = 0; qt < 2; qt++) s[kt][qt] = zero;
#pragma unroll
                for (int dh = 0; dh < 2; dh++) {
#pragma unroll
                    for (int kt = 0; kt < 4; kt++) {
                        f16x8 kf = *(const f16x8*)&Ks[kt * 16 + lr][dh * 32 + quad * 8];
#pragma unroll
                        for (int qt = 0; qt < 2; qt++)
                            s[kt][qt] = __builtin_amdgcn_mfma_f32_16x16x32_f16(kf, qf[qt][dh], s[kt][qt], 0, 0, 0);
                    }
                }
                if (k0 + 63 > wrow0) {
#pragma unroll
                    for (int kt = 0; kt < 4; kt++)
#pragma unroll
                        for (int qt = 0; qt < 2; qt++)
#pragma unroll
                            for (int r = 0; r < 4; r++) {
                                int key = k0 + kt * 16 + quad * 4 + r;
                                int row = wrow0 + qt * 16 + lr;
                                if (key > row) s[kt][qt][r] = -INFINITY;
                            }
                }
                float al[2];
#pragma unroll
                for (int qt = 0; qt < 2; qt++) {
                    float mx = -INFINITY;
#pragma unroll
                    for (int kt = 0; kt < 4; kt++)
#pragma unroll
                        for (int r = 0; r < 4; r++) mx = fmaxf(mx, s[kt][qt][r]);
                    mx = fmaxf(mx, __shfl_xor(mx, 16));
                    mx = fmaxf(mx, __shfl_xor(mx, 32));
                    float mn = fmaxf(m_i[qt], mx);
                    al[qt] = exp2f(m_i[qt] - mn);
                    m_i[qt] = mn;
                }
                union PW { f16x8 v8; f16x2 h2[4]; };
                PW pw[2][2];
                float rs[2] = {0.f, 0.f};
#pragma unroll
                for (int kt = 0; kt < 4; kt++)
#pragma unroll
                    for (int qt = 0; qt < 2; qt++) {
                        float p0 = exp2f(s[kt][qt][0] - m_i[qt]);
                        float p1 = exp2f(s[kt][qt][1] - m_i[qt]);
                        float p2 = exp2f(s[kt][qt][2] - m_i[qt]);
                        float p3 = exp2f(s[kt][qt][3] - m_i[qt]);
                        rs[qt] += (p0 + p1) + (p2 + p3);
                        pw[kt >> 1][qt].h2[(kt & 1) * 2]     = pkrtz(p0, p1);
                        pw[kt >> 1][qt].h2[(kt & 1) * 2 + 1] = pkrtz(p2, p3);
                    }
#pragma unroll
                for (int qt = 0; qt < 2; qt++) l_lane[qt] = l_lane[qt] * al[qt] + rs[qt];
#pragma unroll
                for (int dt = 0; dt < 4; dt++)
#pragma unroll
                    for (int qt = 0; qt < 2; qt++)
#pragma unroll
                        for (int r = 0; r < 4; r++) o[dt][qt][r] *= al[qt];
#pragma unroll
                for (int s2 = 0; s2 < 2; s2++)
#pragma unroll
                    for (int dt = 0; dt < 4; dt++) {
                        f16x4 vlo = *(const f16x4*)&Vt[dt * 16 + lr][s2 * 32 + quad * 4];
                        f16x4 vhi = *(const f16x4*)&Vt[dt * 16 + lr][s2 * 32 + quad * 4 + 16];
                        f16x8 vf;
#pragma unroll
                        for (int e = 0; e < 4; e++) { vf[e] = vlo[e]; vf[e + 4] = vhi[e]; }
#pragma unroll
                        for (int qt = 0; qt < 2; qt++)
                            o[dt][qt] = __builtin_amdgcn_mfma_f32_16x16x32_f16(vf, pw[s2][qt].v8, o[dt][qt], 0, 0, 0);
                    }
            }
        }

        float l_i[2];
#pragma unroll
        for (int qt = 0; qt < 2; qt++) {
            float v2 = l_lane[qt];
            v2 += __shfl_xor(v2, 16);
            v2 += __shfl_xor(v2, 32);
            l_i[qt] = v2;
        }
#pragma unroll
        for (int dt = 0; dt < 4; dt++)
#pragma unroll
            for (int qt = 0; qt < 2; qt++) {
                int row = wrow0 + qt * 16 + lr;
                f16x4 oh = {(f16)o[dt][qt][0], (f16)o[dt][qt][1], (f16)o[dt][qt][2], (f16)o[dt][qt][3]};
                *(f16x4*)&OpartH[((size_t)sp * TSEQ + row) * EMBED + h * DHEAD + dt * 16 + quad * 4] = oh;
            }
#pragma unroll
        for (int qt = 0; qt < 2; qt++)
            if (quad == 0) {
                int row = wrow0 + qt * 16 + lr;
                ml[((size_t)sp * TSEQ + row) * NHEAD + h] = make_float2(m_i[qt], l_i[qt]);
            }
    }
}

// ---------------- merge split-K f16 partials -> ctx f16
__global__ __launch_bounds__(256) void attn_merge_kernel(const f16* __restrict__ OpartH,
                                                         const float2* __restrict__ ml,
                                                         f16* __restrict__ ctx) {
    const int row = blockIdx.x;
    const int t = threadIdx.x;
    __shared__ float wgt[NSPLIT][NHEAD];
    if (t < NHEAD) {
        float m[NSPLIT], l[NSPLIT];
        float M = -INFINITY;
#pragma unroll
        for (int s = 0; s < NSPLIT; s++) {
            float2 v = ml[((size_t)s * TSEQ + row) * NHEAD + t];
            m[s] = v.x; l[s] = v.y;
            M = fmaxf(M, m[s]);
        }
        float L = 0.f;
        float w[NSPLIT];
#pragma unroll
        for (int s = 0; s < NSPLIT; s++) {
            w[s] = exp2f(m[s] - M);
            L += l[s] * w[s];
        }
        float rL = 1.0f / L;
#pragma unroll
        for (int s = 0; s < NSPLIT; s++) wgt[s][t] = w[s] * rL;
    }
    __syncthreads();
#pragma unroll
    for (int p = 0; p < 3; p++) {
        int c = t + p * 256;
        int h = c >> 6;
        float acc = 0.f;
#pragma unroll
        for (int s = 0; s < NSPLIT; s++)
            acc += wgt[s][h] * (float)OpartH[((size_t)s * TSEQ + row) * EMBED + c];
        ctx[(size_t)row * EMBED + c] = (f16)acc;
    }
}

extern "C" void kernel_launch(void* const* d_in, const int* in_sizes, int n_in,
                              void* d_out, int out_size, void* d_ws, size_t ws_size,
                              hipStream_t stream) {
    const float* x     = (const float*)d_in[0];
    const float* Wq    = (const float*)d_in[1];
    const float* bq    = (const float*)d_in[2];
    const float* Wk    = (const float*)d_in[3];
    const float* bk    = (const float*)d_in[4];
    const float* Wv    = (const float*)d_in[5];
    const float* bv    = (const float*)d_in[6];
    const float* Wo    = (const float*)d_in[7];
    const float* bo    = (const float*)d_in[8];
    const float* ln1_g = (const float*)d_in[9];
    const float* ln1_b = (const float*)d_in[10];
    const float* ln2_g = (const float*)d_in[11];
    const float* ln2_b = (const float*)d_in[12];
    const float* W1    = (const float*)d_in[13];
    const float* b1    = (const float*)d_in[14];
    const float* W2    = (const float*)d_in[15];
    const float* b2    = (const float*)d_in[16];

    char* p = (char*)d_ws;
    auto alloc = [&](size_t bytes) -> void* {
        void* r = (void*)p;
        p += (bytes + 255) & ~(size_t)255;
        return r;
    };
    f16*   WqkvT = (f16*)alloc((size_t)CQKV * EMBED * 2);
    f16*   WoT   = (f16*)alloc((size_t)EMBED * EMBED * 2);
    f16*   W1T   = (f16*)alloc((size_t)FFN_D * EMBED * 2);
    f16*   W2T   = (f16*)alloc((size_t)EMBED * FFN_D * 2);
    float* bqkv  = (float*)alloc((size_t)CQKV * 4);
    f16*   hh    = (f16*)alloc((size_t)TSEQ * EMBED * 2);
    f16*   qkv   = (f16*)alloc((size_t)TSEQ * CQKV * 2);   // V third unused (vT direct)
    f16*   vT    = (f16*)alloc((size_t)EMBED * TSEQ * 2);
    f16*   ctx   = (f16*)alloc((size_t)TSEQ * EMBED * 2);
    float* x2    = (float*)alloc((size_t)TSEQ * EMBED * 4);
    f16*   h2h   = (f16*)alloc((size_t)TSEQ * EMBED * 2);
    f16*   m1    = (f16*)alloc((size_t)TSEQ * FFN_D * 2);
    int*   ctr   = (int*)alloc(256);

    // aliases (lifetime-disjoint):
    //   OpartH (25.2 MB f16) = m1 region  (attn+merge finish before FFN1 writes m1)
    //   mlbuf  (1.5 MB)      = x2 region  (merge reads before Wo writes x2)
    f16*    OpartH = m1;
    float2* mlbuf  = (float2*)x2;

    dim3 blk(256);
    prep_kernel<<<dim3(6913), blk, 0, stream>>>(Wq, Wk, Wv, Wo, W1, W2, bq, bk, bv,
                                                WqkvT, WoT, W1T, W2T, bqkv);
    // LN1 -> hh (f16)
    ln_kernel<<<dim3(TSEQ), blk, 0, stream>>>(x, ln1_g, ln1_b, hh);
    // QKV fused GEMM: q scaled by SC2Q; V section written transposed to vT
    gemm_kernel<0, 128, 128><<<dim3(CQKV / 128, TSEQ / 128), blk, 0, stream>>>(
        hh, WqkvT, bqkv, nullptr, nullptr, qkv, vT, TSEQ, CQKV, EMBED);
    // persistent attention (8 XCD queues, NSPLIT=4, 64-key stages) + merge
    (void)hipMemsetAsync(ctr, 0, 256, stream);
    attn_kernel<<<dim3(1536), blk, 0, stream>>>(qkv, vT, OpartH, mlbuf, ctr);
    attn_merge_kernel<<<dim3(TSEQ), blk, 0, stream>>>(OpartH, mlbuf, ctx);
    // Wo GEMM + f16 residual(hh) -> fp32 x2 (overwrites mlbuf alias - dead)
    gemm_kernel<1, 128, 64><<<dim3(EMBED / 64, TSEQ / 128), blk, 0, stream>>>(
        ctx, WoT, bo, hh, x2, nullptr, nullptr, TSEQ, EMBED, EMBED);
    // LN2 -> h2h (f16)
    ln_kernel<<<dim3(TSEQ), blk, 0, stream>>>(x2, ln2_g, ln2_b, h2h);
    // FFN1 + gelu -> m1 (overwrites OpartH alias - dead)
    gemm_kernel<2, 128, 128><<<dim3(FFN_D / 128, TSEQ / 128), blk, 0, stream>>>(
        h2h, W1T, b1, nullptr, nullptr, m1, nullptr, TSEQ, FFN_D, EMBED);
    // FFN2 + f16 residual(h2h) -> fp32 d_out
    gemm_kernel<1, 128, 64><<<dim3(EMBED / 64, TSEQ / 128), blk, 0, stream>>>(
        m1, W2T, b2, h2h, (float*)d_out, nullptr, nullptr, TSEQ, EMBED, FFN_D);
}